// Round 5
// baseline (738.054 us; speedup 1.0000x reference)
//
#include <hip/hip_runtime.h>
#include <math.h>

#define F_   257
#define N_   1000
#define C_   6
#define S_   2
#define K_   4
#define T_   5
#define DLY  6          /* N_TAPS + N_DELAY */
#define EPSF 1e-3f
#define MODEL_EPSF 1e-5f
#define PB_EPSD 1e-6
#define NTHR 512

__device__ __forceinline__ float2 cmul(float2 a, float2 b){
  return make_float2(a.x*b.x - a.y*b.y, a.x*b.y + a.y*b.x);
}
__device__ __forceinline__ float2 cadd(float2 a, float2 b){ return make_float2(a.x+b.x, a.y+b.y); }
__device__ __forceinline__ float2 csub(float2 a, float2 b){ return make_float2(a.x-b.x, a.y-b.y); }

struct dc { double x, y; };
__device__ __forceinline__ dc dmul(dc a, dc b){ return dc{a.x*b.x - a.y*b.y, a.x*b.y + a.y*b.x}; }
__device__ __forceinline__ dc dadd(dc a, dc b){ return dc{a.x+b.x, a.y+b.y}; }
__device__ __forceinline__ dc dsub(dc a, dc b){ return dc{a.x-b.x, a.y-b.y}; }
__device__ __forceinline__ dc ddiv(dc a, dc b){
  double d = b.x*b.x + b.y*b.y;
  return dc{(a.x*b.x + a.y*b.y)/d, (a.y*b.x - a.x*b.y)/d};
}
__device__ __forceinline__ dc d_of(float2 a){ return dc{(double)a.x, (double)a.y}; }

__device__ __forceinline__ float wred(float v){
  #pragma unroll
  for (int off = 32; off; off >>= 1) v += __shfl_xor(v, off);
  return v;
}
__device__ __forceinline__ double wredd(double v){
  #pragma unroll
  for (int off = 32; off; off >>= 1) v += __shfl_xor(v, off);
  return v;
}

// ---------------------------------------------------------------------------
// weights precompute: den[b][s][n] += sum_f |src|^2, gsum[b][s] += total
// ---------------------------------------------------------------------------
__global__ __launch_bounds__(128) void k_weights_x(const float* __restrict__ Xre,
    const float* __restrict__ Xim, float* __restrict__ deng, float* __restrict__ gsumg)
{
  __shared__ float redw[2];
  int blk = blockIdx.x;
  int fc = blk & 15; int ch = (blk >> 4) & 7; int s = (blk >> 7) & 1; int b = blk >> 8;
  int tid = threadIdx.x;
  int n = ch*125 + tid;
  int f0 = fc*17, f1 = (f0 + 17 < F_) ? f0 + 17 : F_;
  float acc = 0.f;
  if (tid < 125){
    for (int f = f0; f < f1; ++f){
      size_t gi = ((size_t)(b*C_+s)*F_ + f)*N_ + n;
      float xr = Xre[gi], xi = Xim[gi];
      acc += xr*xr + xi*xi;
    }
    atomicAdd(&deng[(b*S_+s)*N_ + n], acc);
  }
  float r = (tid < 125) ? acc : 0.f;
  #pragma unroll
  for (int off = 32; off; off >>= 1) r += __shfl_xor(r, off);
  if ((tid & 63) == 0) redw[tid >> 6] = r;
  __syncthreads();
  if (tid == 0) atomicAdd(&gsumg[b*S_+s], redw[0] + redw[1]);
}

__global__ __launch_bounds__(128) void k_weights_y(const float2* __restrict__ Yg,
    float* __restrict__ deng, float* __restrict__ gsumg)
{
  __shared__ float redw[2];
  int blk = blockIdx.x;
  int fc = blk & 15; int ch = (blk >> 4) & 7; int s = (blk >> 7) & 1; int b = blk >> 8;
  int tid = threadIdx.x;
  int n = ch*125 + tid;
  int f0 = fc*17, f1 = (f0 + 17 < F_) ? f0 + 17 : F_;
  float acc = 0.f;
  if (tid < 125){
    for (int f = f0; f < f1; ++f){
      float2 y = Yg[(((size_t)(b*F_+f))*S_ + s)*N_ + n];
      acc += y.x*y.x + y.y*y.y;
    }
    atomicAdd(&deng[(b*S_+s)*N_ + n], acc);
  }
  float r = (tid < 125) ? acc : 0.f;
  #pragma unroll
  for (int off = 32; off; off >>= 1) r += __shfl_xor(r, off);
  if ((tid & 63) == 0) redw[tid >> 6] = r;
  __syncthreads();
  if (tid == 0) atomicAdd(&gsumg[b*S_+s], redw[0] + redw[1]);
}

// ---------------------------------------------------------------------------
// background update; cx/cb pre-offset pointers (LDS or global)
// ---------------------------------------------------------------------------
__device__ __forceinline__ void bg_update(int tid, const float2* Wl,
    const float2* Hl, float2* Al, float2* Jl,
    const float2* cx, const float2* cb)
{
  if (tid < S_*C_){
    int s = tid / C_, j = tid - s*C_;
    float2 a = make_float2(0.f, 0.f);
    #pragma unroll
    for (int i = 0; i < C_; ++i) a = cadd(a, cmul(Wl[s*C_+i], cx[i*C_+j]));
    #pragma unroll
    for (int i = 0; i < C_; ++i)
      #pragma unroll
      for (int t = 0; t < T_; ++t)
        a = cadd(a, cmul(Hl[(s*C_+i)*T_+t], cb[(i*T_+t)*C_+j]));
    Al[s*C_+j] = a;
  }
  __syncthreads();
  if (tid == 0){
    dc M00 = d_of(Al[0]),  M01 = d_of(Al[1]);
    dc M10 = d_of(Al[C_]), M11 = d_of(Al[C_+1]);
    dc det = dsub(dmul(M00, M11), dmul(M01, M10));
    #pragma unroll
    for (int k = 0; k < K_; ++k){
      dc r0 = d_of(Al[2+k]), r1 = d_of(Al[C_+2+k]);
      dc x0 = ddiv(dsub(dmul(M11, r0), dmul(M01, r1)), det);
      dc x1 = ddiv(dsub(dmul(M00, r1), dmul(M10, r0)), det);
      Jl[k*S_+0] = make_float2((float)x0.x, (float)(-x0.y));
      Jl[k*S_+1] = make_float2((float)x1.x, (float)(-x1.y));
    }
  }
  __syncthreads();
}

// ---------------------------------------------------------------------------
// source ISS round (s = current Y[SRC]); Y in LDS, own-frame updates only.
// ---------------------------------------------------------------------------
template<int SRC>
__device__ __forceinline__ void src_round(int tid, int lane, int wid, bool hasB,
    int nA, int nBs, float* redl, float2* Yl, float2* Wl, float2* Hl,
    float wA0, float wA1, float wB0, float wB1)
{
  float2 yA0 = Yl[nA], yA1 = Yl[N_+nA];
  float2 yB0 = Yl[nBs], yB1 = Yl[N_+nBs];
  float2 sA = (SRC==0) ? yA0 : yA1;
  float2 sB = (SRC==0) ? yB0 : yB1;
  float m = sA.x*sA.x + sA.y*sA.y;
  float r0 = wA0*(yA0.x*sA.x + yA0.y*sA.y);
  float r1 = wA0*(yA0.y*sA.x - yA0.x*sA.y);
  float r2 = wA0*m;
  float r3 = wA1*(yA1.x*sA.x + yA1.y*sA.y);
  float r4 = wA1*(yA1.y*sA.x - yA1.x*sA.y);
  float r5 = wA1*m;
  float mb = sB.x*sB.x + sB.y*sB.y;
  r0 += wB0*(yB0.x*sB.x + yB0.y*sB.y);
  r1 += wB0*(yB0.y*sB.x - yB0.x*sB.y);
  r2 += wB0*mb;
  r3 += wB1*(yB1.x*sB.x + yB1.y*sB.y);
  r4 += wB1*(yB1.y*sB.x - yB1.x*sB.y);
  r5 += wB1*mb;
  #pragma unroll
  for (int off = 32; off; off >>= 1){
    r0 += __shfl_xor(r0, off); r1 += __shfl_xor(r1, off);
    r2 += __shfl_xor(r2, off); r3 += __shfl_xor(r3, off);
    r4 += __shfl_xor(r4, off); r5 += __shfl_xor(r5, off);
  }
  if (lane == 0){
    float2* rw = (float2*)(redl + SRC*64 + wid*8);
    rw[0] = make_float2(r0, r1);
    rw[1] = make_float2(r2, r3);
    rw[2] = make_float2(r4, r5);
  }
  __syncthreads();
  float pv = ((lane & 7) < 6) ? redl[SRC*64 + (lane >> 3)*8 + (lane & 7)] : 0.f;
  pv += __shfl_xor(pv, 8);
  pv += __shfl_xor(pv, 16);
  pv += __shfl_xor(pv, 32);
  float t0 = __shfl(pv, 0), t1 = __shfl(pv, 1), t2 = __shfl(pv, 2);
  float t3 = __shfl(pv, 3), t4 = __shfl(pv, 4), t5 = __shfl(pv, 5);
  const float inv = 1.f/(float)N_;
  t0*=inv; t1*=inv; t2*=inv; t3*=inv; t4*=inv; t5*=inv;
  float d0 = fmaxf(t2, EPSF), d1 = fmaxf(t5, EPSF);
  float2 v0 = make_float2(t0/d0, t1/d0);
  float2 v1 = make_float2(t3/d1, t4/d1);
  if (SRC == 0) v0 = make_float2(1.f - 1.f/sqrtf(d0), 0.f);
  else          v1 = make_float2(1.f - 1.f/sqrtf(d1), 0.f);
  Yl[nA]    = csub(yA0, cmul(v0, sA));
  Yl[N_+nA] = csub(yA1, cmul(v1, sA));
  if (hasB){
    Yl[nBs]    = csub(yB0, cmul(v0, sB));
    Yl[N_+nBs] = csub(yB1, cmul(v1, sB));
  }
  if (tid < C_){
    float2 ws = Wl[SRC*C_+tid];
    Wl[tid]    = csub(Wl[tid],    cmul(v0, ws));
    Wl[C_+tid] = csub(Wl[C_+tid], cmul(v1, ws));
  } else if (tid >= 64 && tid < 64 + C_*T_){
    int i = tid - 64;
    float2 hs = Hl[SRC*C_*T_+i];
    Hl[i]       = csub(Hl[i],       cmul(v0, hs));
    Hl[C_*T_+i] = csub(Hl[C_*T_+i], cmul(v1, hs));
  }
}

// ---------------------------------------------------------------------------
// KM: one full _one_iter for one (b,f), blocked-ISS (Gram) formulation.
// Group reductions accumulate in double (classical-GS cancellation guard).
// ---------------------------------------------------------------------------
template<bool FIRST, bool FINAL>
__global__ __launch_bounds__(512, 4) void k_main(const float* __restrict__ Xre,
    const float* __restrict__ Xim, float2* __restrict__ Yg, float2* __restrict__ Wg,
    float2* __restrict__ Hg, float2* __restrict__ Cxxg,
    float2* __restrict__ Cbxg, const float* __restrict__ deng,
    const float* __restrict__ gsumg, float2* __restrict__ out2)
{
  __shared__ float2 Xl[C_*N_];
  __shared__ float2 Yl[S_*N_];
  __shared__ float  wl[S_*N_];
  __shared__ float2 Wl[S_*C_];
  __shared__ float2 Hl[S_*C_*T_];
  __shared__ float2 Jl[K_*S_];
  __shared__ float2 Al[S_*C_];
  __shared__ float  redl[2*64];
  __shared__ dc     AresD[T_][S_];
  __shared__ double DresD[T_][S_];
  __shared__ dc     GresD[10][S_];
  __shared__ float2 Cxl[C_*C_];
  __shared__ float2 Cbl[C_*T_*C_];

  int p = blockIdx.x; int b = p / F_; int f = p - b*F_;
  int tid = threadIdx.x;
  int lane = tid & 63, wid = tid >> 6;
  const int nA = tid;
  const int nB = tid + NTHR;
  const bool hasB = (nB < N_);
  const int nBs = hasB ? nB : 0;

  for (int i = tid; i < C_*N_; i += NTHR){
    int c = i / N_, n = i - c*N_;
    size_t gi = ((size_t)(b*C_+c)*F_ + f)*N_ + n;
    Xl[i] = make_float2(Xre[gi], Xim[gi]);
  }
  if (tid < 128) redl[tid] = 0.f;

  float gv0 = fmaxf(gsumg[b*S_+0] * (1.f/((float)F_*(float)N_)), EPSF);
  float gv1 = fmaxf(gsumg[b*S_+1] * (1.f/((float)F_*(float)N_)), EPSF);
  float ig0 = 1.f / fmaxf(sqrtf(gv0), EPSF);
  float ig1 = 1.f / fmaxf(sqrtf(gv1), EPSF);

  float wA0 = gv0 / fmaxf(2.f*sqrtf(deng[(b*S_+0)*N_+nA]), MODEL_EPSF);
  float wA1 = gv1 / fmaxf(2.f*sqrtf(deng[(b*S_+1)*N_+nA]), MODEL_EPSF);
  float wB0 = 0.f, wB1 = 0.f;
  wl[nA] = wA0; wl[N_+nA] = wA1;
  if (hasB){
    wB0 = gv0 / fmaxf(2.f*sqrtf(deng[(b*S_+0)*N_+nB]), MODEL_EPSF);
    wB1 = gv1 / fmaxf(2.f*sqrtf(deng[(b*S_+1)*N_+nB]), MODEL_EPSF);
    wl[nB] = wB0; wl[N_+nB] = wB1;
  }

  if (FIRST){
    if (tid < S_*C_){
      int s = tid / C_, c = tid - s*C_;
      Wl[tid] = make_float2((s==c) ? (s ? ig1 : ig0) : 0.f, 0.f);
    }
    if (tid < S_*C_*T_) Hl[tid] = make_float2(0.f, 0.f);
  } else {
    if (tid < S_*C_){
      float ig = (tid / C_) ? ig1 : ig0;
      float2 w = Wg[(size_t)p*S_*C_ + tid];
      Wl[tid] = make_float2(w.x*ig, w.y*ig);
    }
    if (tid < S_*C_*T_){
      float ig = (tid / (C_*T_)) ? ig1 : ig0;
      float2 h = Hg[(size_t)p*S_*C_*T_ + tid];
      Hl[tid] = make_float2(h.x*ig, h.y*ig);
    }
  }
  __syncthreads();

  // Y init/load (LDS), scaled
  if (FIRST){
    float2 x0 = Xl[nA], x1 = Xl[N_+nA];
    Yl[nA]    = make_float2(x0.x*ig0, x0.y*ig0);
    Yl[N_+nA] = make_float2(x1.x*ig1, x1.y*ig1);
    if (hasB){
      float2 u0 = Xl[nB], u1 = Xl[N_+nB];
      Yl[nB]    = make_float2(u0.x*ig0, u0.y*ig0);
      Yl[N_+nB] = make_float2(u1.x*ig1, u1.y*ig1);
    }
  } else {
    float2 t0 = Yg[((size_t)p*S_+0)*N_+nA];
    float2 t1 = Yg[((size_t)p*S_+1)*N_+nA];
    Yl[nA]    = make_float2(t0.x*ig0, t0.y*ig0);
    Yl[N_+nA] = make_float2(t1.x*ig1, t1.y*ig1);
    if (hasB){
      float2 u0 = Yg[((size_t)p*S_+0)*N_+nB];
      float2 u1 = Yg[((size_t)p*S_+1)*N_+nB];
      Yl[nB]    = make_float2(u0.x*ig0, u0.y*ig0);
      Yl[N_+nB] = make_float2(u1.x*ig1, u1.y*ig1);
    }
  }

  if (FIRST){
    // covariances from staged Xl -> LDS + global
    const float inv_n = 1.0f / (float)N_;
    for (int e = wid; e < 216; e += 8){
      int a_ch, b_ch, lag;
      if (e < 36){ a_ch = e / 6; b_ch = e - a_ch*6; lag = 0; }
      else {
        int i2 = e - 36;
        a_ch = i2 / (T_*C_); int t = (i2 / C_) % T_; b_ch = i2 % C_;
        lag = DLY - t;
      }
      float accx = 0.f, accy = 0.f;
      for (int n = lane; n < N_; n += 64){
        if (n >= lag){
          float2 xa = Xl[a_ch*N_ + n - lag];
          float2 xb = Xl[b_ch*N_ + n];
          accx += xa.x*xb.x + xa.y*xb.y;
          accy += xa.y*xb.x - xa.x*xb.y;
        }
      }
      accx = wred(accx); accy = wred(accy);
      if (lane == 0){
        float2 r = make_float2(accx*inv_n, accy*inv_n);
        if (e < 36){ Cxl[e] = r; Cxxg[(size_t)p*(C_*C_) + e] = r; }
        else { Cbl[e-36] = r; Cbxg[(size_t)p*(C_*T_*C_) + (e-36)] = r; }
      }
    }
  }
  __syncthreads();

  const float2* cx = FIRST ? (const float2*)Cxl : (const float2*)(Cxxg + (size_t)p*C_*C_);
  const float2* cb = FIRST ? (const float2*)Cbl : (const float2*)(Cbxg + (size_t)p*C_*T_*C_);

  bg_update(tid, Wl, Hl, Al, Jl, cx, cb);

  // ---- source rounds (dynamic direction = Y itself) ----
  src_round<0>(tid, lane, wid, hasB, nA, nBs, redl, Yl, Wl, Hl, wA0, wA1, wB0, wB1);
  src_round<1>(tid, lane, wid, hasB, nA, nBs, redl, Yl, Wl, Hl, wA0, wA1, wB0, wB1);
  __syncthreads();   // Y visible to all waves

  // ---- Z group (4 rounds), batched Gram, double accumulation ----
  {
    for (int tsk = wid; tsk < 10; tsk += 8){
      if (tsk < 4){
        int k = tsk;
        float2 j0 = Jl[k*S_+0], j1 = Jl[k*S_+1];
        double ar0=0,ai0=0,ar1=0,ai1=0,dd0=0,dd1=0;
        for (int n = lane; n < N_; n += 64){
          float2 x0 = Xl[n], x1 = Xl[N_+n];
          float2 z = csub(cadd(cmul(j0,x0), cmul(j1,x1)), Xl[(S_+k)*N_+n]);
          float w0 = wl[n], w1 = wl[N_+n];
          float2 y0 = Yl[n], y1 = Yl[N_+n];
          ar0 += (double)(w0*(y0.x*z.x + y0.y*z.y));
          ai0 += (double)(w0*(y0.y*z.x - y0.x*z.y));
          ar1 += (double)(w1*(y1.x*z.x + y1.y*z.y));
          ai1 += (double)(w1*(y1.y*z.x - y1.x*z.y));
          float m = z.x*z.x + z.y*z.y;
          dd0 += (double)(w0*m); dd1 += (double)(w1*m);
        }
        ar0=wredd(ar0); ai0=wredd(ai0); ar1=wredd(ar1); ai1=wredd(ai1);
        dd0=wredd(dd0); dd1=wredd(dd1);
        if (lane == 0){
          AresD[k][0] = dc{ar0, ai0};
          AresD[k][1] = dc{ar1, ai1};
          DresD[k][0] = dd0; DresD[k][1] = dd1;
        }
      } else {
        int q = tsk - 4;
        int ka = (q < 3) ? 0 : (q < 5 ? 1 : 2);
        int kb = (q < 3) ? (q + 1) : (q < 5 ? (q - 1) : 3);   // FIXED map
        float2 ja0=Jl[ka*S_+0], ja1=Jl[ka*S_+1];
        float2 jb0=Jl[kb*S_+0], jb1=Jl[kb*S_+1];
        double gr0=0,gi0=0,gr1=0,gi1=0;
        for (int n = lane; n < N_; n += 64){
          float2 x0 = Xl[n], x1 = Xl[N_+n];
          float2 za = csub(cadd(cmul(ja0,x0), cmul(ja1,x1)), Xl[(S_+ka)*N_+n]);
          float2 zb = csub(cadd(cmul(jb0,x0), cmul(jb1,x1)), Xl[(S_+kb)*N_+n]);
          float pr = za.x*zb.x + za.y*zb.y;     // za * conj(zb)
          float pi = za.y*zb.x - za.x*zb.y;
          float w0 = wl[n], w1 = wl[N_+n];
          gr0 += (double)(w0*pr); gi0 += (double)(w0*pi);
          gr1 += (double)(w1*pr); gi1 += (double)(w1*pi);
        }
        gr0=wredd(gr0); gi0=wredd(gi0); gr1=wredd(gr1); gi1=wredd(gi1);
        if (lane == 0){
          GresD[q][0] = dc{gr0, gi0};
          GresD[q][1] = dc{gr1, gi1};
        }
      }
    }
    __syncthreads();

    // chain (redundant, double); zbase[i] = {0,3,5}
    float2 vz[K_][S_];
    #pragma unroll
    for (int s = 0; s < S_; ++s){
      dc av[K_];
      #pragma unroll
      for (int k = 0; k < K_; ++k) av[k] = AresD[k][s];
      #pragma unroll
      for (int i = 0; i < K_; ++i){
        double dd = fmax(DresD[i][s], (double)EPSF);
        float2 v = make_float2((float)(av[i].x/dd), (float)(av[i].y/dd));
        vz[i][s] = v;
        dc vd = dc{(double)v.x, (double)v.y};
        #pragma unroll
        for (int j = i+1; j < K_; ++j){
          const int zbase = (i==0) ? 0 : (i==1) ? 3 : 5;
          int q = zbase + (j - i - 1);
          av[j] = dsub(av[j], dmul(vd, GresD[q][s]));
        }
      }
    }
    // deferred Y update (own frames)
    {
      float2 x0 = Xl[nA], x1 = Xl[N_+nA];
      float2 y0 = Yl[nA], y1 = Yl[N_+nA];
      #pragma unroll
      for (int k = 0; k < K_; ++k){
        float2 z = csub(cadd(cmul(Jl[k*S_+0], x0), cmul(Jl[k*S_+1], x1)), Xl[(S_+k)*N_+nA]);
        y0 = csub(y0, cmul(vz[k][0], z));
        y1 = csub(y1, cmul(vz[k][1], z));
      }
      Yl[nA] = y0; Yl[N_+nA] = y1;
      if (hasB){
        float2 u0 = Xl[nB], u1 = Xl[N_+nB];
        float2 p0 = Yl[nB], p1 = Yl[N_+nB];
        #pragma unroll
        for (int k = 0; k < K_; ++k){
          float2 z = csub(cadd(cmul(Jl[k*S_+0], u0), cmul(Jl[k*S_+1], u1)), Xl[(S_+k)*N_+nB]);
          p0 = csub(p0, cmul(vz[k][0], z));
          p1 = csub(p1, cmul(vz[k][1], z));
        }
        Yl[nB] = p0; Yl[N_+nB] = p1;
      }
    }
    // W updates (fixed J => all 4 rounds commute)
    if (tid == 0){
      #pragma unroll
      for (int s = 0; s < S_; ++s)
        #pragma unroll
        for (int k = 0; k < K_; ++k){
          Wl[s*C_+0]    = csub(Wl[s*C_+0], cmul(vz[k][s], Jl[k*S_+0]));
          Wl[s*C_+1]    = csub(Wl[s*C_+1], cmul(vz[k][s], Jl[k*S_+1]));
          Wl[s*C_+S_+k] = cadd(Wl[s*C_+S_+k], vz[k][s]);
        }
    }
    __syncthreads();
  }

  // ---- tap groups: channel c, 5 lags {6,5,4,3,2} ----
  for (int c = 0; c < C_; ++c){
    const float2* Xc = Xl + c*N_;
    for (int tsk = wid; tsk < 15; tsk += 8){
      if (tsk < 5){
        int lag = DLY - tsk;
        double ar0=0,ai0=0,ar1=0,ai1=0,dd0=0,dd1=0;
        for (int n = lane; n < N_; n += 64){
          float2 x = (n >= lag) ? Xc[n-lag] : make_float2(0.f,0.f);
          float w0 = wl[n], w1 = wl[N_+n];
          float2 y0 = Yl[n], y1 = Yl[N_+n];
          ar0 += (double)(w0*(y0.x*x.x + y0.y*x.y));
          ai0 += (double)(w0*(y0.y*x.x - y0.x*x.y));
          ar1 += (double)(w1*(y1.x*x.x + y1.y*x.y));
          ai1 += (double)(w1*(y1.y*x.x - y1.x*x.y));
          float m = x.x*x.x + x.y*x.y;
          dd0 += (double)(w0*m); dd1 += (double)(w1*m);
        }
        ar0=wredd(ar0); ai0=wredd(ai0); ar1=wredd(ar1); ai1=wredd(ai1);
        dd0=wredd(dd0); dd1=wredd(dd1);
        if (lane == 0){
          AresD[tsk][0] = dc{ar0, ai0};
          AresD[tsk][1] = dc{ar1, ai1};
          DresD[tsk][0] = dd0; DresD[tsk][1] = dd1;
        }
      } else {
        int q = tsk - 5;
        int ta = (q < 4) ? 0 : (q < 7) ? 1 : (q < 9) ? 2 : 3;
        int tb = (q < 4) ? (q + 1) : (q < 7) ? (q - 2) : (q < 9) ? (q - 4) : 4;
        int l1 = DLY - ta, l2 = DLY - tb;
        double gr0=0,gi0=0,gr1=0,gi1=0;
        for (int n = lane; n < N_; n += 64){
          float2 x1 = (n >= l1) ? Xc[n-l1] : make_float2(0.f,0.f);
          float2 x2 = (n >= l2) ? Xc[n-l2] : make_float2(0.f,0.f);
          float pr = x1.x*x2.x + x1.y*x2.y;     // x_l1 * conj(x_l2)
          float pi = x1.y*x2.x - x1.x*x2.y;
          float w0 = wl[n], w1 = wl[N_+n];
          gr0 += (double)(w0*pr); gi0 += (double)(w0*pi);
          gr1 += (double)(w1*pr); gi1 += (double)(w1*pi);
        }
        gr0=wredd(gr0); gi0=wredd(gi0); gr1=wredd(gr1); gi1=wredd(gi1);
        if (lane == 0){
          GresD[q][0] = dc{gr0, gi0};
          GresD[q][1] = dc{gr1, gi1};
        }
      }
    }
    __syncthreads();

    // chain (redundant, double); base[i] = {0,4,7,9}
    float2 vt[T_][S_];
    #pragma unroll
    for (int s = 0; s < S_; ++s){
      dc av[T_];
      #pragma unroll
      for (int t = 0; t < T_; ++t) av[t] = AresD[t][s];
      #pragma unroll
      for (int i = 0; i < T_; ++i){
        double dd = fmax(DresD[i][s], (double)EPSF);
        float2 v = make_float2((float)(av[i].x/dd), (float)(av[i].y/dd));
        vt[i][s] = v;
        dc vd = dc{(double)v.x, (double)v.y};
        #pragma unroll
        for (int j = i+1; j < T_; ++j){
          const int base = (i==0) ? 0 : (i==1) ? 4 : (i==2) ? 7 : 9;
          int q = base + (j - i - 1);
          av[j] = dsub(av[j], dmul(vd, GresD[q][s]));
        }
      }
    }
    // deferred Y update
    {
      float2 y0 = Yl[nA], y1 = Yl[N_+nA];
      #pragma unroll
      for (int t = 0; t < T_; ++t){
        int lag = DLY - t;
        float2 x = (nA >= lag) ? Xc[nA-lag] : make_float2(0.f,0.f);
        y0 = csub(y0, cmul(vt[t][0], x));
        y1 = csub(y1, cmul(vt[t][1], x));
      }
      Yl[nA] = y0; Yl[N_+nA] = y1;
      if (hasB){
        float2 p0 = Yl[nB], p1 = Yl[N_+nB];
        #pragma unroll
        for (int t = 0; t < T_; ++t){
          int lag = DLY - t;
          float2 x = Xc[nB-lag];
          p0 = csub(p0, cmul(vt[t][0], x));
          p1 = csub(p1, cmul(vt[t][1], x));
        }
        Yl[nB] = p0; Yl[N_+nB] = p1;
      }
    }
    // H updates
    if (tid == 0){
      #pragma unroll
      for (int s = 0; s < S_; ++s)
        #pragma unroll
        for (int t = 0; t < T_; ++t){
          int idx = (s*C_+c)*T_+t;
          Hl[idx] = cadd(Hl[idx], vt[t][s]);
        }
    }
    __syncthreads();
  }

  if (!FINAL){
    Yg[((size_t)p*S_+0)*N_+nA] = Yl[nA];
    Yg[((size_t)p*S_+1)*N_+nA] = Yl[N_+nA];
    if (hasB){
      Yg[((size_t)p*S_+0)*N_+nB] = Yl[nB];
      Yg[((size_t)p*S_+1)*N_+nB] = Yl[N_+nB];
    }
    if (tid < S_*C_)    Wg[(size_t)p*S_*C_ + tid]    = Wl[tid];
    if (tid < S_*C_*T_) Hg[(size_t)p*S_*C_*T_ + tid] = Hl[tid];
  } else {
    bg_update(tid, Wl, Hl, Al, Jl, cx, cb);   // final J

    float2 oA0 = make_float2(0.f,0.f), oA1 = oA0, oB0 = oA0, oB1 = oA0;
    #pragma unroll
    for (int d = 0; d < C_; ++d){
      float2 x = Xl[d*N_+nA];
      oA0 = cadd(oA0, cmul(Wl[d],    x));
      oA1 = cadd(oA1, cmul(Wl[C_+d], x));
    }
    #pragma unroll
    for (int t = 0; t < T_; ++t){
      int m = nA - (DLY - t);
      if (m >= 0){
        #pragma unroll
        for (int d = 0; d < C_; ++d){
          float2 x = Xl[d*N_+m];
          oA0 = csub(oA0, cmul(Hl[d*T_+t],      x));
          oA1 = csub(oA1, cmul(Hl[(C_+d)*T_+t], x));
        }
      }
    }
    if (hasB){
      #pragma unroll
      for (int d = 0; d < C_; ++d){
        float2 x = Xl[d*N_+nB];
        oB0 = cadd(oB0, cmul(Wl[d],    x));
        oB1 = cadd(oB1, cmul(Wl[C_+d], x));
      }
      #pragma unroll
      for (int t = 0; t < T_; ++t){
        int m = nB - (DLY - t);
        #pragma unroll
        for (int d = 0; d < C_; ++d){
          float2 x = Xl[d*N_+m];
          oB0 = csub(oB0, cmul(Hl[d*T_+t],      x));
          oB1 = csub(oB1, cmul(Hl[(C_+d)*T_+t], x));
        }
      }
    }

    if (tid == 0){
      dc Bm[2][2];
      #pragma unroll
      for (int s2 = 0; s2 < S_; ++s2)
        #pragma unroll
        for (int k = 0; k < S_; ++k){
          dc acc = d_of(Wl[s2*C_+k]);
          #pragma unroll
          for (int cc = 0; cc < K_; ++cc)
            acc = dadd(acc, dmul(d_of(Wl[s2*C_+S_+cc]), d_of(Jl[cc*S_+k])));
          Bm[s2][k] = acc;
        }
      dc G00 = dc{Bm[0][0].x + PB_EPSD, Bm[0][0].y};
      dc G01 = Bm[1][0];
      dc G10 = Bm[0][1];
      dc G11 = dc{Bm[1][1].x + PB_EPSD, Bm[1][1].y};
      dc det = dsub(dmul(G00, G11), dmul(G01, G10));
      dc a0 = ddiv(G11, det);
      dc a1 = ddiv(dc{-G10.x, -G10.y}, det);
      Al[0] = make_float2((float)a0.x, (float)a0.y);
      Al[1] = make_float2((float)a1.x, (float)a1.y);
    }
    __syncthreads();
    float2 s0 = Al[0], s1 = Al[1];
    out2[((size_t)(b*S_+0)*F_ + f)*N_ + nA] = cmul(oA0, s0);
    out2[((size_t)(b*S_+1)*F_ + f)*N_ + nA] = cmul(oA1, s1);
    if (hasB){
      out2[((size_t)(b*S_+0)*F_ + f)*N_ + nB] = cmul(oB0, s0);
      out2[((size_t)(b*S_+1)*F_ + f)*N_ + nB] = cmul(oB1, s1);
    }
  }
}

// ---------------------------------------------------------------------------
extern "C" void kernel_launch(void* const* d_in, const int* in_sizes, int n_in,
                              void* d_out, int out_size, void* d_ws, size_t ws_size,
                              hipStream_t stream)
{
  const float* Xre = (const float*)d_in[0];
  const float* Xim = (const float*)d_in[1];
  int B = in_sizes[0] / (C_*F_*N_);
  int P = B*F_;

  float2* Yg    = (float2*)d_ws;
  float2* Wg    = Yg    + (size_t)P*S_*N_;
  float2* Hg    = Wg    + (size_t)P*S_*C_;
  float2* Cxxg  = Hg    + (size_t)P*S_*C_*T_;
  float2* Cbxg  = Cxxg  + (size_t)P*C_*C_;
  float*  deng0 = (float*)(Cbxg + (size_t)P*C_*T_*C_);
  float*  deng1 = deng0 + (size_t)B*S_*N_;
  float*  gsum0 = deng1 + (size_t)B*S_*N_;
  float*  gsum1 = gsum0 + (size_t)B*S_;
  float2* out2  = (float2*)d_out;

  size_t zeroBytes = (2*(size_t)B*S_*N_ + 2*(size_t)B*S_) * sizeof(float);
  int WG = B*S_*8*16;

  hipMemsetAsync(deng0, 0, zeroBytes, stream);
  // iteration 0 (covariances computed inside k_main<FIRST>)
  k_weights_x<<<WG, 128, 0, stream>>>(Xre, Xim, deng0, gsum0);
  k_main<true,false><<<P, 512, 0, stream>>>(Xre, Xim, Yg, Wg, Hg, Cxxg, Cbxg,
                                            deng0, gsum0, nullptr);
  // iteration 1 + finalization
  k_weights_y<<<WG, 128, 0, stream>>>(Yg, deng1, gsum1);
  k_main<false,true><<<P, 512, 0, stream>>>(Xre, Xim, Yg, Wg, Hg, Cxxg, Cbxg,
                                            deng1, gsum1, out2);
}

// Round 7
// 686.179 us; speedup vs baseline: 1.0756x; 1.0756x over previous
//
#include <hip/hip_runtime.h>
#include <math.h>

#define F_   257
#define N_   1000
#define C_   6
#define S_   2
#define K_   4
#define T_   5
#define DLY  6          /* N_TAPS + N_DELAY */
#define EPSF 1e-3f
#define MODEL_EPSF 1e-5f
#define PB_EPSD 1e-6
#define NTHR 512

__device__ __forceinline__ float2 cmul(float2 a, float2 b){
  return make_float2(a.x*b.x - a.y*b.y, a.x*b.y + a.y*b.x);
}
__device__ __forceinline__ float2 cadd(float2 a, float2 b){ return make_float2(a.x+b.x, a.y+b.y); }
__device__ __forceinline__ float2 csub(float2 a, float2 b){ return make_float2(a.x-b.x, a.y-b.y); }

struct dc { double x, y; };
__device__ __forceinline__ dc dmul(dc a, dc b){ return dc{a.x*b.x - a.y*b.y, a.x*b.y + a.y*b.x}; }
__device__ __forceinline__ dc dadd(dc a, dc b){ return dc{a.x+b.x, a.y+b.y}; }
__device__ __forceinline__ dc dsub(dc a, dc b){ return dc{a.x-b.x, a.y-b.y}; }
__device__ __forceinline__ dc ddiv(dc a, dc b){
  double d = b.x*b.x + b.y*b.y;
  return dc{(a.x*b.x + a.y*b.y)/d, (a.y*b.x - a.x*b.y)/d};
}
__device__ __forceinline__ dc d_of(float2 a){ return dc{(double)a.x, (double)a.y}; }

__device__ __forceinline__ float wred(float v){
  #pragma unroll
  for (int off = 32; off; off >>= 1) v += __shfl_xor(v, off);
  return v;
}
__device__ __forceinline__ double wredd(double v){
  #pragma unroll
  for (int off = 32; off; off >>= 1) v += __shfl_xor(v, off);
  return v;
}

// ---------------------------------------------------------------------------
// weights precompute: den[b][s][n] += sum_f |src|^2, gsum[b][s] += total
// ---------------------------------------------------------------------------
__global__ __launch_bounds__(128) void k_weights_x(const float* __restrict__ Xre,
    const float* __restrict__ Xim, float* __restrict__ deng, float* __restrict__ gsumg)
{
  __shared__ float redw[2];
  int blk = blockIdx.x;
  int fc = blk & 15; int ch = (blk >> 4) & 7; int s = (blk >> 7) & 1; int b = blk >> 8;
  int tid = threadIdx.x;
  int n = ch*125 + tid;
  int f0 = fc*17, f1 = (f0 + 17 < F_) ? f0 + 17 : F_;
  float acc = 0.f;
  if (tid < 125){
    for (int f = f0; f < f1; ++f){
      size_t gi = ((size_t)(b*C_+s)*F_ + f)*N_ + n;
      float xr = Xre[gi], xi = Xim[gi];
      acc += xr*xr + xi*xi;
    }
    atomicAdd(&deng[(b*S_+s)*N_ + n], acc);
  }
  float r = (tid < 125) ? acc : 0.f;
  #pragma unroll
  for (int off = 32; off; off >>= 1) r += __shfl_xor(r, off);
  if ((tid & 63) == 0) redw[tid >> 6] = r;
  __syncthreads();
  if (tid == 0) atomicAdd(&gsumg[b*S_+s], redw[0] + redw[1]);
}

__global__ __launch_bounds__(128) void k_weights_y(const float2* __restrict__ Yg,
    float* __restrict__ deng, float* __restrict__ gsumg)
{
  __shared__ float redw[2];
  int blk = blockIdx.x;
  int fc = blk & 15; int ch = (blk >> 4) & 7; int s = (blk >> 7) & 1; int b = blk >> 8;
  int tid = threadIdx.x;
  int n = ch*125 + tid;
  int f0 = fc*17, f1 = (f0 + 17 < F_) ? f0 + 17 : F_;
  float acc = 0.f;
  if (tid < 125){
    for (int f = f0; f < f1; ++f){
      float2 y = Yg[(((size_t)(b*F_+f))*S_ + s)*N_ + n];
      acc += y.x*y.x + y.y*y.y;
    }
    atomicAdd(&deng[(b*S_+s)*N_ + n], acc);
  }
  float r = (tid < 125) ? acc : 0.f;
  #pragma unroll
  for (int off = 32; off; off >>= 1) r += __shfl_xor(r, off);
  if ((tid & 63) == 0) redw[tid >> 6] = r;
  __syncthreads();
  if (tid == 0) atomicAdd(&gsumg[b*S_+s], redw[0] + redw[1]);
}

// ---------------------------------------------------------------------------
// background update; cx/cb pre-offset pointers (LDS or global)
// ---------------------------------------------------------------------------
__device__ __forceinline__ void bg_update(int tid, const float2* Wl,
    const float2* Hl, float2* Al, float2* Jl,
    const float2* cx, const float2* cb)
{
  if (tid < S_*C_){
    int s = tid / C_, j = tid - s*C_;
    float2 a = make_float2(0.f, 0.f);
    #pragma unroll
    for (int i = 0; i < C_; ++i) a = cadd(a, cmul(Wl[s*C_+i], cx[i*C_+j]));
    #pragma unroll
    for (int i = 0; i < C_; ++i)
      #pragma unroll
      for (int t = 0; t < T_; ++t)
        a = cadd(a, cmul(Hl[(s*C_+i)*T_+t], cb[(i*T_+t)*C_+j]));
    Al[s*C_+j] = a;
  }
  __syncthreads();
  if (tid == 0){
    dc M00 = d_of(Al[0]),  M01 = d_of(Al[1]);
    dc M10 = d_of(Al[C_]), M11 = d_of(Al[C_+1]);
    dc det = dsub(dmul(M00, M11), dmul(M01, M10));
    #pragma unroll
    for (int k = 0; k < K_; ++k){
      dc r0 = d_of(Al[2+k]), r1 = d_of(Al[C_+2+k]);
      dc x0 = ddiv(dsub(dmul(M11, r0), dmul(M01, r1)), det);
      dc x1 = ddiv(dsub(dmul(M00, r1), dmul(M10, r0)), det);
      Jl[k*S_+0] = make_float2((float)x0.x, (float)(-x0.y));
      Jl[k*S_+1] = make_float2((float)x1.x, (float)(-x1.y));
    }
  }
  __syncthreads();
}

// ---------------------------------------------------------------------------
// source ISS round (s = current Y[SRC]); Y in LDS, own-frame updates only.
// ---------------------------------------------------------------------------
template<int SRC>
__device__ __forceinline__ void src_round(int tid, int lane, int wid, bool hasB,
    int nA, int nBs, float* redl, float2* Yl, float2* Wl, float2* Hl,
    float wA0, float wA1, float wB0, float wB1)
{
  float2 yA0 = Yl[nA], yA1 = Yl[N_+nA];
  float2 yB0 = Yl[nBs], yB1 = Yl[N_+nBs];
  float2 sA = (SRC==0) ? yA0 : yA1;
  float2 sB = (SRC==0) ? yB0 : yB1;
  float m = sA.x*sA.x + sA.y*sA.y;
  float r0 = wA0*(yA0.x*sA.x + yA0.y*sA.y);
  float r1 = wA0*(yA0.y*sA.x - yA0.x*sA.y);
  float r2 = wA0*m;
  float r3 = wA1*(yA1.x*sA.x + yA1.y*sA.y);
  float r4 = wA1*(yA1.y*sA.x - yA1.x*sA.y);
  float r5 = wA1*m;
  float mb = sB.x*sB.x + sB.y*sB.y;
  r0 += wB0*(yB0.x*sB.x + yB0.y*sB.y);
  r1 += wB0*(yB0.y*sB.x - yB0.x*sB.y);
  r2 += wB0*mb;
  r3 += wB1*(yB1.x*sB.x + yB1.y*sB.y);
  r4 += wB1*(yB1.y*sB.x - yB1.x*sB.y);
  r5 += wB1*mb;
  #pragma unroll
  for (int off = 32; off; off >>= 1){
    r0 += __shfl_xor(r0, off); r1 += __shfl_xor(r1, off);
    r2 += __shfl_xor(r2, off); r3 += __shfl_xor(r3, off);
    r4 += __shfl_xor(r4, off); r5 += __shfl_xor(r5, off);
  }
  if (lane == 0){
    float2* rw = (float2*)(redl + SRC*64 + wid*8);
    rw[0] = make_float2(r0, r1);
    rw[1] = make_float2(r2, r3);
    rw[2] = make_float2(r4, r5);
  }
  __syncthreads();
  float pv = ((lane & 7) < 6) ? redl[SRC*64 + (lane >> 3)*8 + (lane & 7)] : 0.f;
  pv += __shfl_xor(pv, 8);
  pv += __shfl_xor(pv, 16);
  pv += __shfl_xor(pv, 32);
  float t0 = __shfl(pv, 0), t1 = __shfl(pv, 1), t2 = __shfl(pv, 2);
  float t3 = __shfl(pv, 3), t4 = __shfl(pv, 4), t5 = __shfl(pv, 5);
  const float inv = 1.f/(float)N_;
  t0*=inv; t1*=inv; t2*=inv; t3*=inv; t4*=inv; t5*=inv;
  float d0 = fmaxf(t2, EPSF), d1 = fmaxf(t5, EPSF);
  float2 v0 = make_float2(t0/d0, t1/d0);
  float2 v1 = make_float2(t3/d1, t4/d1);
  if (SRC == 0) v0 = make_float2(1.f - 1.f/sqrtf(d0), 0.f);
  else          v1 = make_float2(1.f - 1.f/sqrtf(d1), 0.f);
  Yl[nA]    = csub(yA0, cmul(v0, sA));
  Yl[N_+nA] = csub(yA1, cmul(v1, sA));
  if (hasB){
    Yl[nBs]    = csub(yB0, cmul(v0, sB));
    Yl[N_+nBs] = csub(yB1, cmul(v1, sB));
  }
  if (tid < C_){
    float2 ws = Wl[SRC*C_+tid];
    Wl[tid]    = csub(Wl[tid],    cmul(v0, ws));
    Wl[C_+tid] = csub(Wl[C_+tid], cmul(v1, ws));
  } else if (tid >= 64 && tid < 64 + C_*T_){
    int i = tid - 64;
    float2 hs = Hl[SRC*C_*T_+i];
    Hl[i]       = csub(Hl[i],       cmul(v0, hs));
    Hl[C_*T_+i] = csub(Hl[C_*T_+i], cmul(v1, hs));
  }
}

// ---------------------------------------------------------------------------
// chain solvers: read LDS A/D/G, emit v's as named scalars (no reg arrays).
// Z map: G[0..2]=(0,1),(0,2),(0,3)  G[3..4]=(1,2),(1,3)  G[5]=(2,3)
// ---------------------------------------------------------------------------
__device__ __forceinline__ void chainZ(int s, const dc (*A)[S_],
    const double (*D)[S_], const dc (*G)[S_],
    float2& v0, float2& v1, float2& v2, float2& v3)
{
  dc a0 = A[0][s], a1 = A[1][s], a2 = A[2][s], a3 = A[3][s];
  double d; dc vd;
  d = fmax(D[0][s], (double)EPSF);
  v0 = make_float2((float)(a0.x/d), (float)(a0.y/d));
  vd = dc{(double)v0.x, (double)v0.y};
  a1 = dsub(a1, dmul(vd, G[0][s]));
  a2 = dsub(a2, dmul(vd, G[1][s]));
  a3 = dsub(a3, dmul(vd, G[2][s]));
  d = fmax(D[1][s], (double)EPSF);
  v1 = make_float2((float)(a1.x/d), (float)(a1.y/d));
  vd = dc{(double)v1.x, (double)v1.y};
  a2 = dsub(a2, dmul(vd, G[3][s]));
  a3 = dsub(a3, dmul(vd, G[4][s]));
  d = fmax(D[2][s], (double)EPSF);
  v2 = make_float2((float)(a2.x/d), (float)(a2.y/d));
  vd = dc{(double)v2.x, (double)v2.y};
  a3 = dsub(a3, dmul(vd, G[5][s]));
  d = fmax(D[3][s], (double)EPSF);
  v3 = make_float2((float)(a3.x/d), (float)(a3.y/d));
}

// T map: G[0..3]=(0,1..4)  G[4..6]=(1,2..4)  G[7..8]=(2,3..4)  G[9]=(3,4)
__device__ __forceinline__ void chainT(int s, const dc (*A)[S_],
    const double (*D)[S_], const dc (*G)[S_],
    float2& v0, float2& v1, float2& v2, float2& v3, float2& v4)
{
  dc a0 = A[0][s], a1 = A[1][s], a2 = A[2][s], a3 = A[3][s], a4 = A[4][s];
  double d; dc vd;
  d = fmax(D[0][s], (double)EPSF);
  v0 = make_float2((float)(a0.x/d), (float)(a0.y/d));
  vd = dc{(double)v0.x, (double)v0.y};
  a1 = dsub(a1, dmul(vd, G[0][s]));
  a2 = dsub(a2, dmul(vd, G[1][s]));
  a3 = dsub(a3, dmul(vd, G[2][s]));
  a4 = dsub(a4, dmul(vd, G[3][s]));
  d = fmax(D[1][s], (double)EPSF);
  v1 = make_float2((float)(a1.x/d), (float)(a1.y/d));
  vd = dc{(double)v1.x, (double)v1.y};
  a2 = dsub(a2, dmul(vd, G[4][s]));
  a3 = dsub(a3, dmul(vd, G[5][s]));
  a4 = dsub(a4, dmul(vd, G[6][s]));
  d = fmax(D[2][s], (double)EPSF);
  v2 = make_float2((float)(a2.x/d), (float)(a2.y/d));
  vd = dc{(double)v2.x, (double)v2.y};
  a3 = dsub(a3, dmul(vd, G[7][s]));
  a4 = dsub(a4, dmul(vd, G[8][s]));
  d = fmax(D[3][s], (double)EPSF);
  v3 = make_float2((float)(a3.x/d), (float)(a3.y/d));
  vd = dc{(double)v3.x, (double)v3.y};
  a4 = dsub(a4, dmul(vd, G[9][s]));
  d = fmax(D[4][s], (double)EPSF);
  v4 = make_float2((float)(a4.x/d), (float)(a4.y/d));
}

// ---------------------------------------------------------------------------
// KM: one full _one_iter for one (b,f), blocked-ISS (Gram) formulation.
// Group reductions accumulate in double (scalar accumulators only).
// ---------------------------------------------------------------------------
template<bool FIRST, bool FINAL>
__global__ __launch_bounds__(512, 2) void k_main(const float* __restrict__ Xre,
    const float* __restrict__ Xim, float2* __restrict__ Yg, float2* __restrict__ Wg,
    float2* __restrict__ Hg, float2* __restrict__ Cxxg,
    float2* __restrict__ Cbxg, const float* __restrict__ deng,
    const float* __restrict__ gsumg, float2* __restrict__ out2)
{
  __shared__ float2 Xl[C_*N_];
  __shared__ float2 Yl[S_*N_];
  __shared__ float  wl[S_*N_];
  __shared__ float2 Wl[S_*C_];
  __shared__ float2 Hl[S_*C_*T_];
  __shared__ float2 Jl[K_*S_];
  __shared__ float2 Al[S_*C_];
  __shared__ float  redl[2*64];
  __shared__ dc     AresD[T_][S_];
  __shared__ double DresD[T_][S_];
  __shared__ dc     GresD[10][S_];
  __shared__ float2 Cxl[C_*C_];
  __shared__ float2 Cbl[C_*T_*C_];

  int p = blockIdx.x; int b = p / F_; int f = p - b*F_;
  int tid = threadIdx.x;
  int lane = tid & 63, wid = tid >> 6;
  const int nA = tid;
  const int nB = tid + NTHR;
  const bool hasB = (nB < N_);
  const int nBs = hasB ? nB : 0;

  for (int i = tid; i < C_*N_; i += NTHR){
    int c = i / N_, n = i - c*N_;
    size_t gi = ((size_t)(b*C_+c)*F_ + f)*N_ + n;
    Xl[i] = make_float2(Xre[gi], Xim[gi]);
  }
  if (tid < 128) redl[tid] = 0.f;

  float gv0 = fmaxf(gsumg[b*S_+0] * (1.f/((float)F_*(float)N_)), EPSF);
  float gv1 = fmaxf(gsumg[b*S_+1] * (1.f/((float)F_*(float)N_)), EPSF);
  float ig0 = 1.f / fmaxf(sqrtf(gv0), EPSF);
  float ig1 = 1.f / fmaxf(sqrtf(gv1), EPSF);

  float wA0 = gv0 / fmaxf(2.f*sqrtf(deng[(b*S_+0)*N_+nA]), MODEL_EPSF);
  float wA1 = gv1 / fmaxf(2.f*sqrtf(deng[(b*S_+1)*N_+nA]), MODEL_EPSF);
  float wB0 = 0.f, wB1 = 0.f;
  wl[nA] = wA0; wl[N_+nA] = wA1;
  if (hasB){
    wB0 = gv0 / fmaxf(2.f*sqrtf(deng[(b*S_+0)*N_+nB]), MODEL_EPSF);
    wB1 = gv1 / fmaxf(2.f*sqrtf(deng[(b*S_+1)*N_+nB]), MODEL_EPSF);
    wl[nB] = wB0; wl[N_+nB] = wB1;
  }

  if (FIRST){
    if (tid < S_*C_){
      int s = tid / C_, c = tid - s*C_;
      Wl[tid] = make_float2((s==c) ? (s ? ig1 : ig0) : 0.f, 0.f);
    }
    if (tid < S_*C_*T_) Hl[tid] = make_float2(0.f, 0.f);
  } else {
    if (tid < S_*C_){
      float ig = (tid / C_) ? ig1 : ig0;
      float2 w = Wg[(size_t)p*S_*C_ + tid];
      Wl[tid] = make_float2(w.x*ig, w.y*ig);
    }
    if (tid < S_*C_*T_){
      float ig = (tid / (C_*T_)) ? ig1 : ig0;
      float2 h = Hg[(size_t)p*S_*C_*T_ + tid];
      Hl[tid] = make_float2(h.x*ig, h.y*ig);
    }
  }
  __syncthreads();

  // Y init/load (LDS), scaled
  if (FIRST){
    float2 x0 = Xl[nA], x1 = Xl[N_+nA];
    Yl[nA]    = make_float2(x0.x*ig0, x0.y*ig0);
    Yl[N_+nA] = make_float2(x1.x*ig1, x1.y*ig1);
    if (hasB){
      float2 u0 = Xl[nB], u1 = Xl[N_+nB];
      Yl[nB]    = make_float2(u0.x*ig0, u0.y*ig0);
      Yl[N_+nB] = make_float2(u1.x*ig1, u1.y*ig1);
    }
  } else {
    float2 t0 = Yg[((size_t)p*S_+0)*N_+nA];
    float2 t1 = Yg[((size_t)p*S_+1)*N_+nA];
    Yl[nA]    = make_float2(t0.x*ig0, t0.y*ig0);
    Yl[N_+nA] = make_float2(t1.x*ig1, t1.y*ig1);
    if (hasB){
      float2 u0 = Yg[((size_t)p*S_+0)*N_+nB];
      float2 u1 = Yg[((size_t)p*S_+1)*N_+nB];
      Yl[nB]    = make_float2(u0.x*ig0, u0.y*ig0);
      Yl[N_+nB] = make_float2(u1.x*ig1, u1.y*ig1);
    }
  }

  if (FIRST){
    // covariances from staged Xl -> LDS + global
    const float inv_n = 1.0f / (float)N_;
    for (int e = wid; e < 216; e += 8){
      int a_ch, b_ch, lag;
      if (e < 36){ a_ch = e / 6; b_ch = e - a_ch*6; lag = 0; }
      else {
        int i2 = e - 36;
        a_ch = i2 / (T_*C_); int t = (i2 / C_) % T_; b_ch = i2 % C_;
        lag = DLY - t;
      }
      float accx = 0.f, accy = 0.f;
      for (int n = lane; n < N_; n += 64){
        if (n >= lag){
          float2 xa = Xl[a_ch*N_ + n - lag];
          float2 xb = Xl[b_ch*N_ + n];
          accx += xa.x*xb.x + xa.y*xb.y;
          accy += xa.y*xb.x - xa.x*xb.y;
        }
      }
      accx = wred(accx); accy = wred(accy);
      if (lane == 0){
        float2 r = make_float2(accx*inv_n, accy*inv_n);
        if (e < 36){ Cxl[e] = r; Cxxg[(size_t)p*(C_*C_) + e] = r; }
        else { Cbl[e-36] = r; Cbxg[(size_t)p*(C_*T_*C_) + (e-36)] = r; }
      }
    }
  }
  __syncthreads();

  const float2* cx = FIRST ? (const float2*)Cxl : (const float2*)(Cxxg + (size_t)p*C_*C_);
  const float2* cb = FIRST ? (const float2*)Cbl : (const float2*)(Cbxg + (size_t)p*C_*T_*C_);

  bg_update(tid, Wl, Hl, Al, Jl, cx, cb);

  // ---- source rounds (dynamic direction = Y itself) ----
  src_round<0>(tid, lane, wid, hasB, nA, nBs, redl, Yl, Wl, Hl, wA0, wA1, wB0, wB1);
  src_round<1>(tid, lane, wid, hasB, nA, nBs, redl, Yl, Wl, Hl, wA0, wA1, wB0, wB1);
  __syncthreads();   // Y visible to all waves

  // ---- Z group (4 rounds), batched Gram, double scalar accumulation ----
  {
    for (int tsk = wid; tsk < 10; tsk += 8){
      if (tsk < 4){
        int k = tsk;
        float2 j0 = Jl[k*S_+0], j1 = Jl[k*S_+1];
        double ar0=0,ai0=0,ar1=0,ai1=0,dd0=0,dd1=0;
        for (int n = lane; n < N_; n += 64){
          float2 x0 = Xl[n], x1 = Xl[N_+n];
          float2 z = csub(cadd(cmul(j0,x0), cmul(j1,x1)), Xl[(S_+k)*N_+n]);
          float w0 = wl[n], w1 = wl[N_+n];
          float2 y0 = Yl[n], y1 = Yl[N_+n];
          ar0 += (double)(w0*(y0.x*z.x + y0.y*z.y));
          ai0 += (double)(w0*(y0.y*z.x - y0.x*z.y));
          ar1 += (double)(w1*(y1.x*z.x + y1.y*z.y));
          ai1 += (double)(w1*(y1.y*z.x - y1.x*z.y));
          float m = z.x*z.x + z.y*z.y;
          dd0 += (double)(w0*m); dd1 += (double)(w1*m);
        }
        ar0=wredd(ar0); ai0=wredd(ai0); ar1=wredd(ar1); ai1=wredd(ai1);
        dd0=wredd(dd0); dd1=wredd(dd1);
        if (lane == 0){
          AresD[k][0] = dc{ar0, ai0};
          AresD[k][1] = dc{ar1, ai1};
          DresD[k][0] = dd0; DresD[k][1] = dd1;
        }
      } else {
        int q = tsk - 4;
        int ka = (q < 3) ? 0 : (q < 5 ? 1 : 2);
        int kb = (q < 3) ? (q + 1) : (q < 5 ? (q - 1) : 3);
        float2 ja0=Jl[ka*S_+0], ja1=Jl[ka*S_+1];
        float2 jb0=Jl[kb*S_+0], jb1=Jl[kb*S_+1];
        double gr0=0,gi0=0,gr1=0,gi1=0;
        for (int n = lane; n < N_; n += 64){
          float2 x0 = Xl[n], x1 = Xl[N_+n];
          float2 za = csub(cadd(cmul(ja0,x0), cmul(ja1,x1)), Xl[(S_+ka)*N_+n]);
          float2 zb = csub(cadd(cmul(jb0,x0), cmul(jb1,x1)), Xl[(S_+kb)*N_+n]);
          float pr = za.x*zb.x + za.y*zb.y;     // za * conj(zb)
          float pi = za.y*zb.x - za.x*zb.y;
          float w0 = wl[n], w1 = wl[N_+n];
          gr0 += (double)(w0*pr); gi0 += (double)(w0*pi);
          gr1 += (double)(w1*pr); gi1 += (double)(w1*pi);
        }
        gr0=wredd(gr0); gi0=wredd(gi0); gr1=wredd(gr1); gi1=wredd(gi1);
        if (lane == 0){
          GresD[q][0] = dc{gr0, gi0};
          GresD[q][1] = dc{gr1, gi1};
        }
      }
    }
    __syncthreads();

    // chain (redundant, named scalars)
    float2 vz0s0, vz1s0, vz2s0, vz3s0;
    float2 vz0s1, vz1s1, vz2s1, vz3s1;
    chainZ(0, AresD, DresD, GresD, vz0s0, vz1s0, vz2s0, vz3s0);
    chainZ(1, AresD, DresD, GresD, vz0s1, vz1s1, vz2s1, vz3s1);

    // deferred Y update (own frames)
    {
      float2 x0 = Xl[nA], x1 = Xl[N_+nA];
      float2 y0 = Yl[nA], y1 = Yl[N_+nA];
      float2 z;
      z = csub(cadd(cmul(Jl[0], x0), cmul(Jl[1], x1)), Xl[(S_+0)*N_+nA]);
      y0 = csub(y0, cmul(vz0s0, z)); y1 = csub(y1, cmul(vz0s1, z));
      z = csub(cadd(cmul(Jl[2], x0), cmul(Jl[3], x1)), Xl[(S_+1)*N_+nA]);
      y0 = csub(y0, cmul(vz1s0, z)); y1 = csub(y1, cmul(vz1s1, z));
      z = csub(cadd(cmul(Jl[4], x0), cmul(Jl[5], x1)), Xl[(S_+2)*N_+nA]);
      y0 = csub(y0, cmul(vz2s0, z)); y1 = csub(y1, cmul(vz2s1, z));
      z = csub(cadd(cmul(Jl[6], x0), cmul(Jl[7], x1)), Xl[(S_+3)*N_+nA]);
      y0 = csub(y0, cmul(vz3s0, z)); y1 = csub(y1, cmul(vz3s1, z));
      Yl[nA] = y0; Yl[N_+nA] = y1;
      if (hasB){
        float2 u0 = Xl[nB], u1 = Xl[N_+nB];
        float2 p0 = Yl[nB], p1 = Yl[N_+nB];
        z = csub(cadd(cmul(Jl[0], u0), cmul(Jl[1], u1)), Xl[(S_+0)*N_+nB]);
        p0 = csub(p0, cmul(vz0s0, z)); p1 = csub(p1, cmul(vz0s1, z));
        z = csub(cadd(cmul(Jl[2], u0), cmul(Jl[3], u1)), Xl[(S_+1)*N_+nB]);
        p0 = csub(p0, cmul(vz1s0, z)); p1 = csub(p1, cmul(vz1s1, z));
        z = csub(cadd(cmul(Jl[4], u0), cmul(Jl[5], u1)), Xl[(S_+2)*N_+nB]);
        p0 = csub(p0, cmul(vz2s0, z)); p1 = csub(p1, cmul(vz2s1, z));
        z = csub(cadd(cmul(Jl[6], u0), cmul(Jl[7], u1)), Xl[(S_+3)*N_+nB]);
        p0 = csub(p0, cmul(vz3s0, z)); p1 = csub(p1, cmul(vz3s1, z));
        Yl[nB] = p0; Yl[N_+nB] = p1;
      }
    }
    // W updates (fixed J => rounds commute)
    if (tid == 0){
      Wl[0] = csub(Wl[0], cadd(cadd(cmul(vz0s0,Jl[0]), cmul(vz1s0,Jl[2])),
                               cadd(cmul(vz2s0,Jl[4]), cmul(vz3s0,Jl[6]))));
      Wl[1] = csub(Wl[1], cadd(cadd(cmul(vz0s0,Jl[1]), cmul(vz1s0,Jl[3])),
                               cadd(cmul(vz2s0,Jl[5]), cmul(vz3s0,Jl[7]))));
      Wl[S_+0] = cadd(Wl[S_+0], vz0s0);
      Wl[S_+1] = cadd(Wl[S_+1], vz1s0);
      Wl[S_+2] = cadd(Wl[S_+2], vz2s0);
      Wl[S_+3] = cadd(Wl[S_+3], vz3s0);
      Wl[C_+0] = csub(Wl[C_+0], cadd(cadd(cmul(vz0s1,Jl[0]), cmul(vz1s1,Jl[2])),
                                     cadd(cmul(vz2s1,Jl[4]), cmul(vz3s1,Jl[6]))));
      Wl[C_+1] = csub(Wl[C_+1], cadd(cadd(cmul(vz0s1,Jl[1]), cmul(vz1s1,Jl[3])),
                                     cadd(cmul(vz2s1,Jl[5]), cmul(vz3s1,Jl[7]))));
      Wl[C_+S_+0] = cadd(Wl[C_+S_+0], vz0s1);
      Wl[C_+S_+1] = cadd(Wl[C_+S_+1], vz1s1);
      Wl[C_+S_+2] = cadd(Wl[C_+S_+2], vz2s1);
      Wl[C_+S_+3] = cadd(Wl[C_+S_+3], vz3s1);
    }
    __syncthreads();
  }

  // ---- tap groups: channel c, 5 lags {6,5,4,3,2} ----
  for (int c = 0; c < C_; ++c){
    const float2* Xc = Xl + c*N_;
    for (int tsk = wid; tsk < 15; tsk += 8){
      if (tsk < 5){
        int lag = DLY - tsk;
        double ar0=0,ai0=0,ar1=0,ai1=0,dd0=0,dd1=0;
        for (int n = lane; n < N_; n += 64){
          float2 x = (n >= lag) ? Xc[n-lag] : make_float2(0.f,0.f);
          float w0 = wl[n], w1 = wl[N_+n];
          float2 y0 = Yl[n], y1 = Yl[N_+n];
          ar0 += (double)(w0*(y0.x*x.x + y0.y*x.y));
          ai0 += (double)(w0*(y0.y*x.x - y0.x*x.y));
          ar1 += (double)(w1*(y1.x*x.x + y1.y*x.y));
          ai1 += (double)(w1*(y1.y*x.x - y1.x*x.y));
          float m = x.x*x.x + x.y*x.y;
          dd0 += (double)(w0*m); dd1 += (double)(w1*m);
        }
        ar0=wredd(ar0); ai0=wredd(ai0); ar1=wredd(ar1); ai1=wredd(ai1);
        dd0=wredd(dd0); dd1=wredd(dd1);
        if (lane == 0){
          AresD[tsk][0] = dc{ar0, ai0};
          AresD[tsk][1] = dc{ar1, ai1};
          DresD[tsk][0] = dd0; DresD[tsk][1] = dd1;
        }
      } else {
        int q = tsk - 5;
        int ta = (q < 4) ? 0 : (q < 7) ? 1 : (q < 9) ? 2 : 3;
        int tb = (q < 4) ? (q + 1) : (q < 7) ? (q - 2) : (q < 9) ? (q - 4) : 4;
        int l1 = DLY - ta, l2 = DLY - tb;
        double gr0=0,gi0=0,gr1=0,gi1=0;
        for (int n = lane; n < N_; n += 64){
          float2 x1 = (n >= l1) ? Xc[n-l1] : make_float2(0.f,0.f);
          float2 x2 = (n >= l2) ? Xc[n-l2] : make_float2(0.f,0.f);
          float pr = x1.x*x2.x + x1.y*x2.y;     // x_l1 * conj(x_l2)
          float pi = x1.y*x2.x - x1.x*x2.y;
          float w0 = wl[n], w1 = wl[N_+n];
          gr0 += (double)(w0*pr); gi0 += (double)(w0*pi);
          gr1 += (double)(w1*pr); gi1 += (double)(w1*pi);
        }
        gr0=wredd(gr0); gi0=wredd(gi0); gr1=wredd(gr1); gi1=wredd(gi1);
        if (lane == 0){
          GresD[q][0] = dc{gr0, gi0};
          GresD[q][1] = dc{gr1, gi1};
        }
      }
    }
    __syncthreads();

    // chain (redundant, named scalars)
    float2 vt0s0, vt1s0, vt2s0, vt3s0, vt4s0;
    float2 vt0s1, vt1s1, vt2s1, vt3s1, vt4s1;
    chainT(0, AresD, DresD, GresD, vt0s0, vt1s0, vt2s0, vt3s0, vt4s0);
    chainT(1, AresD, DresD, GresD, vt0s1, vt1s1, vt2s1, vt3s1, vt4s1);

    // deferred Y update
    {
      float2 y0 = Yl[nA], y1 = Yl[N_+nA];
      float2 x;
      x = (nA >= 6) ? Xc[nA-6] : make_float2(0.f,0.f);
      y0 = csub(y0, cmul(vt0s0, x)); y1 = csub(y1, cmul(vt0s1, x));
      x = (nA >= 5) ? Xc[nA-5] : make_float2(0.f,0.f);
      y0 = csub(y0, cmul(vt1s0, x)); y1 = csub(y1, cmul(vt1s1, x));
      x = (nA >= 4) ? Xc[nA-4] : make_float2(0.f,0.f);
      y0 = csub(y0, cmul(vt2s0, x)); y1 = csub(y1, cmul(vt2s1, x));
      x = (nA >= 3) ? Xc[nA-3] : make_float2(0.f,0.f);
      y0 = csub(y0, cmul(vt3s0, x)); y1 = csub(y1, cmul(vt3s1, x));
      x = (nA >= 2) ? Xc[nA-2] : make_float2(0.f,0.f);
      y0 = csub(y0, cmul(vt4s0, x)); y1 = csub(y1, cmul(vt4s1, x));
      Yl[nA] = y0; Yl[N_+nA] = y1;
      if (hasB){
        float2 p0 = Yl[nB], p1 = Yl[N_+nB];
        x = Xc[nB-6]; p0 = csub(p0, cmul(vt0s0, x)); p1 = csub(p1, cmul(vt0s1, x));
        x = Xc[nB-5]; p0 = csub(p0, cmul(vt1s0, x)); p1 = csub(p1, cmul(vt1s1, x));
        x = Xc[nB-4]; p0 = csub(p0, cmul(vt2s0, x)); p1 = csub(p1, cmul(vt2s1, x));
        x = Xc[nB-3]; p0 = csub(p0, cmul(vt3s0, x)); p1 = csub(p1, cmul(vt3s1, x));
        x = Xc[nB-2]; p0 = csub(p0, cmul(vt4s0, x)); p1 = csub(p1, cmul(vt4s1, x));
        Yl[nB] = p0; Yl[N_+nB] = p1;
      }
    }
    // H updates
    if (tid == 0){
      Hl[(0*C_+c)*T_+0] = cadd(Hl[(0*C_+c)*T_+0], vt0s0);
      Hl[(0*C_+c)*T_+1] = cadd(Hl[(0*C_+c)*T_+1], vt1s0);
      Hl[(0*C_+c)*T_+2] = cadd(Hl[(0*C_+c)*T_+2], vt2s0);
      Hl[(0*C_+c)*T_+3] = cadd(Hl[(0*C_+c)*T_+3], vt3s0);
      Hl[(0*C_+c)*T_+4] = cadd(Hl[(0*C_+c)*T_+4], vt4s0);
      Hl[(1*C_+c)*T_+0] = cadd(Hl[(1*C_+c)*T_+0], vt0s1);
      Hl[(1*C_+c)*T_+1] = cadd(Hl[(1*C_+c)*T_+1], vt1s1);
      Hl[(1*C_+c)*T_+2] = cadd(Hl[(1*C_+c)*T_+2], vt2s1);
      Hl[(1*C_+c)*T_+3] = cadd(Hl[(1*C_+c)*T_+3], vt3s1);
      Hl[(1*C_+c)*T_+4] = cadd(Hl[(1*C_+c)*T_+4], vt4s1);
    }
    __syncthreads();
  }

  if (!FINAL){
    Yg[((size_t)p*S_+0)*N_+nA] = Yl[nA];
    Yg[((size_t)p*S_+1)*N_+nA] = Yl[N_+nA];
    if (hasB){
      Yg[((size_t)p*S_+0)*N_+nB] = Yl[nB];
      Yg[((size_t)p*S_+1)*N_+nB] = Yl[N_+nB];
    }
    if (tid < S_*C_)    Wg[(size_t)p*S_*C_ + tid]    = Wl[tid];
    if (tid < S_*C_*T_) Hg[(size_t)p*S_*C_*T_ + tid] = Hl[tid];
  } else {
    bg_update(tid, Wl, Hl, Al, Jl, cx, cb);   // final J

    float2 oA0 = make_float2(0.f,0.f), oA1 = oA0, oB0 = oA0, oB1 = oA0;
    #pragma unroll
    for (int d = 0; d < C_; ++d){
      float2 x = Xl[d*N_+nA];
      oA0 = cadd(oA0, cmul(Wl[d],    x));
      oA1 = cadd(oA1, cmul(Wl[C_+d], x));
    }
    #pragma unroll
    for (int t = 0; t < T_; ++t){
      int m = nA - (DLY - t);
      if (m >= 0){
        #pragma unroll
        for (int d = 0; d < C_; ++d){
          float2 x = Xl[d*N_+m];
          oA0 = csub(oA0, cmul(Hl[d*T_+t],      x));
          oA1 = csub(oA1, cmul(Hl[(C_+d)*T_+t], x));
        }
      }
    }
    if (hasB){
      #pragma unroll
      for (int d = 0; d < C_; ++d){
        float2 x = Xl[d*N_+nB];
        oB0 = cadd(oB0, cmul(Wl[d],    x));
        oB1 = cadd(oB1, cmul(Wl[C_+d], x));
      }
      #pragma unroll
      for (int t = 0; t < T_; ++t){
        int m = nB - (DLY - t);
        #pragma unroll
        for (int d = 0; d < C_; ++d){
          float2 x = Xl[d*N_+m];
          oB0 = csub(oB0, cmul(Hl[d*T_+t],      x));
          oB1 = csub(oB1, cmul(Hl[(C_+d)*T_+t], x));
        }
      }
    }

    if (tid == 0){
      dc Bm[2][2];
      #pragma unroll
      for (int s2 = 0; s2 < S_; ++s2)
        #pragma unroll
        for (int k = 0; k < S_; ++k){
          dc acc = d_of(Wl[s2*C_+k]);
          #pragma unroll
          for (int cc = 0; cc < K_; ++cc)
            acc = dadd(acc, dmul(d_of(Wl[s2*C_+S_+cc]), d_of(Jl[cc*S_+k])));
          Bm[s2][k] = acc;
        }
      dc G00 = dc{Bm[0][0].x + PB_EPSD, Bm[0][0].y};
      dc G01 = Bm[1][0];
      dc G10 = Bm[0][1];
      dc G11 = dc{Bm[1][1].x + PB_EPSD, Bm[1][1].y};
      dc det = dsub(dmul(G00, G11), dmul(G01, G10));
      dc a0 = ddiv(G11, det);
      dc a1 = ddiv(dc{-G10.x, -G10.y}, det);
      Al[0] = make_float2((float)a0.x, (float)a0.y);
      Al[1] = make_float2((float)a1.x, (float)a1.y);
    }
    __syncthreads();
    float2 s0 = Al[0], s1 = Al[1];
    out2[((size_t)(b*S_+0)*F_ + f)*N_ + nA] = cmul(oA0, s0);
    out2[((size_t)(b*S_+1)*F_ + f)*N_ + nA] = cmul(oA1, s1);
    if (hasB){
      out2[((size_t)(b*S_+0)*F_ + f)*N_ + nB] = cmul(oB0, s0);
      out2[((size_t)(b*S_+1)*F_ + f)*N_ + nB] = cmul(oB1, s1);
    }
  }
}

// ---------------------------------------------------------------------------
extern "C" void kernel_launch(void* const* d_in, const int* in_sizes, int n_in,
                              void* d_out, int out_size, void* d_ws, size_t ws_size,
                              hipStream_t stream)
{
  const float* Xre = (const float*)d_in[0];
  const float* Xim = (const float*)d_in[1];
  int B = in_sizes[0] / (C_*F_*N_);
  int P = B*F_;

  float2* Yg    = (float2*)d_ws;
  float2* Wg    = Yg    + (size_t)P*S_*N_;
  float2* Hg    = Wg    + (size_t)P*S_*C_;
  float2* Cxxg  = Hg    + (size_t)P*S_*C_*T_;
  float2* Cbxg  = Cxxg  + (size_t)P*C_*C_;
  float*  deng0 = (float*)(Cbxg + (size_t)P*C_*T_*C_);
  float*  deng1 = deng0 + (size_t)B*S_*N_;
  float*  gsum0 = deng1 + (size_t)B*S_*N_;
  float*  gsum1 = gsum0 + (size_t)B*S_;
  float2* out2  = (float2*)d_out;

  size_t zeroBytes = (2*(size_t)B*S_*N_ + 2*(size_t)B*S_) * sizeof(float);
  int WG = B*S_*8*16;

  hipMemsetAsync(deng0, 0, zeroBytes, stream);
  // iteration 0 (covariances computed inside k_main<FIRST>)
  k_weights_x<<<WG, 128, 0, stream>>>(Xre, Xim, deng0, gsum0);
  k_main<true,false><<<P, 512, 0, stream>>>(Xre, Xim, Yg, Wg, Hg, Cxxg, Cbxg,
                                            deng0, gsum0, nullptr);
  // iteration 1 + finalization
  k_weights_y<<<WG, 128, 0, stream>>>(Yg, deng1, gsum1);
  k_main<false,true><<<P, 512, 0, stream>>>(Xre, Xim, Yg, Wg, Hg, Cxxg, Cbxg,
                                            deng1, gsum1, out2);
}

// Round 8
// 647.437 us; speedup vs baseline: 1.1400x; 1.0598x over previous
//
#include <hip/hip_runtime.h>
#include <math.h>

#define F_   257
#define N_   1000
#define C_   6
#define S_   2
#define K_   4
#define T_   5
#define DLY  6          /* N_TAPS + N_DELAY */
#define EPSF 1e-3f
#define MODEL_EPSF 1e-5f
#define PB_EPSD 1e-6
#define NTHR 512

__device__ __forceinline__ float2 cmul(float2 a, float2 b){
  return make_float2(a.x*b.x - a.y*b.y, a.x*b.y + a.y*b.x);
}
__device__ __forceinline__ float2 cadd(float2 a, float2 b){ return make_float2(a.x+b.x, a.y+b.y); }
__device__ __forceinline__ float2 csub(float2 a, float2 b){ return make_float2(a.x-b.x, a.y-b.y); }

struct dc { double x, y; };
__device__ __forceinline__ dc dmul(dc a, dc b){ return dc{a.x*b.x - a.y*b.y, a.x*b.y + a.y*b.x}; }
__device__ __forceinline__ dc dadd(dc a, dc b){ return dc{a.x+b.x, a.y+b.y}; }
__device__ __forceinline__ dc dsub(dc a, dc b){ return dc{a.x-b.x, a.y-b.y}; }
__device__ __forceinline__ dc ddiv(dc a, dc b){
  double d = b.x*b.x + b.y*b.y;
  return dc{(a.x*b.x + a.y*b.y)/d, (a.y*b.x - a.x*b.y)/d};
}
__device__ __forceinline__ dc d_of(float2 a){ return dc{(double)a.x, (double)a.y}; }

__device__ __forceinline__ float wred(float v){
  #pragma unroll
  for (int off = 32; off; off >>= 1) v += __shfl_xor(v, off);
  return v;
}

// ---------------------------------------------------------------------------
// weights precompute: den[b][s][n] += sum_f |src|^2, gsum[b][s] += total
// ---------------------------------------------------------------------------
__global__ __launch_bounds__(128) void k_weights_x(const float* __restrict__ Xre,
    const float* __restrict__ Xim, float* __restrict__ deng, float* __restrict__ gsumg)
{
  __shared__ float redw[2];
  int blk = blockIdx.x;
  int fc = blk & 15; int ch = (blk >> 4) & 7; int s = (blk >> 7) & 1; int b = blk >> 8;
  int tid = threadIdx.x;
  int n = ch*125 + tid;
  int f0 = fc*17, f1 = (f0 + 17 < F_) ? f0 + 17 : F_;
  float acc = 0.f;
  if (tid < 125){
    for (int f = f0; f < f1; ++f){
      size_t gi = ((size_t)(b*C_+s)*F_ + f)*N_ + n;
      float xr = Xre[gi], xi = Xim[gi];
      acc += xr*xr + xi*xi;
    }
    atomicAdd(&deng[(b*S_+s)*N_ + n], acc);
  }
  float r = (tid < 125) ? acc : 0.f;
  #pragma unroll
  for (int off = 32; off; off >>= 1) r += __shfl_xor(r, off);
  if ((tid & 63) == 0) redw[tid >> 6] = r;
  __syncthreads();
  if (tid == 0) atomicAdd(&gsumg[b*S_+s], redw[0] + redw[1]);
}

__global__ __launch_bounds__(128) void k_weights_y(const float2* __restrict__ Yg,
    float* __restrict__ deng, float* __restrict__ gsumg)
{
  __shared__ float redw[2];
  int blk = blockIdx.x;
  int fc = blk & 15; int ch = (blk >> 4) & 7; int s = (blk >> 7) & 1; int b = blk >> 8;
  int tid = threadIdx.x;
  int n = ch*125 + tid;
  int f0 = fc*17, f1 = (f0 + 17 < F_) ? f0 + 17 : F_;
  float acc = 0.f;
  if (tid < 125){
    for (int f = f0; f < f1; ++f){
      float2 y = Yg[(((size_t)(b*F_+f))*S_ + s)*N_ + n];
      acc += y.x*y.x + y.y*y.y;
    }
    atomicAdd(&deng[(b*S_+s)*N_ + n], acc);
  }
  float r = (tid < 125) ? acc : 0.f;
  #pragma unroll
  for (int off = 32; off; off >>= 1) r += __shfl_xor(r, off);
  if ((tid & 63) == 0) redw[tid >> 6] = r;
  __syncthreads();
  if (tid == 0) atomicAdd(&gsumg[b*S_+s], redw[0] + redw[1]);
}

// ---------------------------------------------------------------------------
// background update; cx/cb pre-offset pointers (LDS or global)
// ---------------------------------------------------------------------------
__device__ __forceinline__ void bg_update(int tid, const float2* Wl,
    const float2* Hl, float2* Al, float2* Jl,
    const float2* cx, const float2* cb)
{
  if (tid < S_*C_){
    int s = tid / C_, j = tid - s*C_;
    float2 a = make_float2(0.f, 0.f);
    #pragma unroll
    for (int i = 0; i < C_; ++i) a = cadd(a, cmul(Wl[s*C_+i], cx[i*C_+j]));
    #pragma unroll
    for (int i = 0; i < C_; ++i)
      #pragma unroll
      for (int t = 0; t < T_; ++t)
        a = cadd(a, cmul(Hl[(s*C_+i)*T_+t], cb[(i*T_+t)*C_+j]));
    Al[s*C_+j] = a;
  }
  __syncthreads();
  if (tid == 0){
    dc M00 = d_of(Al[0]),  M01 = d_of(Al[1]);
    dc M10 = d_of(Al[C_]), M11 = d_of(Al[C_+1]);
    dc det = dsub(dmul(M00, M11), dmul(M01, M10));
    #pragma unroll
    for (int k = 0; k < K_; ++k){
      dc r0 = d_of(Al[2+k]), r1 = d_of(Al[C_+2+k]);
      dc x0 = ddiv(dsub(dmul(M11, r0), dmul(M01, r1)), det);
      dc x1 = ddiv(dsub(dmul(M00, r1), dmul(M10, r0)), det);
      Jl[k*S_+0] = make_float2((float)x0.x, (float)(-x0.y));
      Jl[k*S_+1] = make_float2((float)x1.x, (float)(-x1.y));
    }
  }
  __syncthreads();
}

// ---------------------------------------------------------------------------
// source ISS round (s = current Y[SRC]); Y in LDS, own-frame updates only.
// ---------------------------------------------------------------------------
template<int SRC>
__device__ __forceinline__ void src_round(int tid, int lane, int wid, bool hasB,
    int nA, int nBs, float* redl, float2* Yl, float2* Wl, float2* Hl,
    float wA0, float wA1, float wB0, float wB1)
{
  float2 yA0 = Yl[nA], yA1 = Yl[N_+nA];
  float2 yB0 = Yl[nBs], yB1 = Yl[N_+nBs];
  float2 sA = (SRC==0) ? yA0 : yA1;
  float2 sB = (SRC==0) ? yB0 : yB1;
  float m = sA.x*sA.x + sA.y*sA.y;
  float r0 = wA0*(yA0.x*sA.x + yA0.y*sA.y);
  float r1 = wA0*(yA0.y*sA.x - yA0.x*sA.y);
  float r2 = wA0*m;
  float r3 = wA1*(yA1.x*sA.x + yA1.y*sA.y);
  float r4 = wA1*(yA1.y*sA.x - yA1.x*sA.y);
  float r5 = wA1*m;
  float mb = sB.x*sB.x + sB.y*sB.y;
  r0 += wB0*(yB0.x*sB.x + yB0.y*sB.y);
  r1 += wB0*(yB0.y*sB.x - yB0.x*sB.y);
  r2 += wB0*mb;
  r3 += wB1*(yB1.x*sB.x + yB1.y*sB.y);
  r4 += wB1*(yB1.y*sB.x - yB1.x*sB.y);
  r5 += wB1*mb;
  #pragma unroll
  for (int off = 32; off; off >>= 1){
    r0 += __shfl_xor(r0, off); r1 += __shfl_xor(r1, off);
    r2 += __shfl_xor(r2, off); r3 += __shfl_xor(r3, off);
    r4 += __shfl_xor(r4, off); r5 += __shfl_xor(r5, off);
  }
  if (lane == 0){
    float2* rw = (float2*)(redl + SRC*64 + wid*8);
    rw[0] = make_float2(r0, r1);
    rw[1] = make_float2(r2, r3);
    rw[2] = make_float2(r4, r5);
  }
  __syncthreads();
  float pv = ((lane & 7) < 6) ? redl[SRC*64 + (lane >> 3)*8 + (lane & 7)] : 0.f;
  pv += __shfl_xor(pv, 8);
  pv += __shfl_xor(pv, 16);
  pv += __shfl_xor(pv, 32);
  float t0 = __shfl(pv, 0), t1 = __shfl(pv, 1), t2 = __shfl(pv, 2);
  float t3 = __shfl(pv, 3), t4 = __shfl(pv, 4), t5 = __shfl(pv, 5);
  const float inv = 1.f/(float)N_;
  t0*=inv; t1*=inv; t2*=inv; t3*=inv; t4*=inv; t5*=inv;
  float d0 = fmaxf(t2, EPSF), d1 = fmaxf(t5, EPSF);
  float2 v0 = make_float2(t0/d0, t1/d0);
  float2 v1 = make_float2(t3/d1, t4/d1);
  if (SRC == 0) v0 = make_float2(1.f - 1.f/sqrtf(d0), 0.f);
  else          v1 = make_float2(1.f - 1.f/sqrtf(d1), 0.f);
  Yl[nA]    = csub(yA0, cmul(v0, sA));
  Yl[N_+nA] = csub(yA1, cmul(v1, sA));
  if (hasB){
    Yl[nBs]    = csub(yB0, cmul(v0, sB));
    Yl[N_+nBs] = csub(yB1, cmul(v1, sB));
  }
  if (tid < C_){
    float2 ws = Wl[SRC*C_+tid];
    Wl[tid]    = csub(Wl[tid],    cmul(v0, ws));
    Wl[C_+tid] = csub(Wl[C_+tid], cmul(v1, ws));
  } else if (tid >= 64 && tid < 64 + C_*T_){
    int i = tid - 64;
    float2 hs = Hl[SRC*C_*T_+i];
    Hl[i]       = csub(Hl[i],       cmul(v0, hs));
    Hl[C_*T_+i] = csub(Hl[C_*T_+i], cmul(v1, hs));
  }
}

// ---------------------------------------------------------------------------
// merged tap G-anchor task: pairs (I, I+1..4); fully static indices.
// G map: base(I) = {0,4,7,9}
// ---------------------------------------------------------------------------
template<int I>
__device__ __forceinline__ void tapG(int lane, const float2* Xc, const float* wl,
                                     float2 (*GresF)[S_])
{
  constexpr int NP = 4 - I;
  constexpr int BASE = (I==0)?0:(I==1)?4:(I==2)?7:9;
  float grr[NP][2], gri[NP][2];
  #pragma unroll
  for (int q = 0; q < NP; ++q){
    grr[q][0]=0.f; grr[q][1]=0.f; gri[q][0]=0.f; gri[q][1]=0.f;
  }
  const int lagI = DLY - I;
  for (int n = lane; n < N_; n += 64){
    float2 xi = (n >= lagI) ? Xc[n-lagI] : make_float2(0.f,0.f);
    float w0 = wl[n], w1 = wl[N_+n];
    #pragma unroll
    for (int q = 0; q < NP; ++q){
      const int lagJ = DLY - (I + 1 + q);
      float2 xj = (n >= lagJ) ? Xc[n-lagJ] : make_float2(0.f,0.f);
      float pr = xi.x*xj.x + xi.y*xj.y;   // x_I * conj(x_J)
      float pi = xi.y*xj.x - xi.x*xj.y;
      grr[q][0] += w0*pr; gri[q][0] += w0*pi;
      grr[q][1] += w1*pr; gri[q][1] += w1*pi;
    }
  }
  #pragma unroll
  for (int q = 0; q < NP; ++q)
    #pragma unroll
    for (int s = 0; s < 2; ++s){
      float a = wred(grr[q][s]), b = wred(gri[q][s]);
      if (lane == 0) GresF[BASE+q][s] = make_float2(a, b);
    }
}

// ---------------------------------------------------------------------------
// chain solvers (double math over f32 LDS results, outside hot loops)
// Z map: G[0..2]=(0,1),(0,2),(0,3)  G[3..4]=(1,2),(1,3)  G[5]=(2,3)
// ---------------------------------------------------------------------------
__device__ __forceinline__ void chainZ(int s, const float2 (*A)[S_],
    const float (*D)[S_], const float2 (*G)[S_],
    float2& v0, float2& v1, float2& v2, float2& v3)
{
  dc a0 = d_of(A[0][s]), a1 = d_of(A[1][s]), a2 = d_of(A[2][s]), a3 = d_of(A[3][s]);
  double d; dc vd;
  d = fmax((double)D[0][s], (double)EPSF);
  v0 = make_float2((float)(a0.x/d), (float)(a0.y/d));
  vd = dc{(double)v0.x, (double)v0.y};
  a1 = dsub(a1, dmul(vd, d_of(G[0][s])));
  a2 = dsub(a2, dmul(vd, d_of(G[1][s])));
  a3 = dsub(a3, dmul(vd, d_of(G[2][s])));
  d = fmax((double)D[1][s], (double)EPSF);
  v1 = make_float2((float)(a1.x/d), (float)(a1.y/d));
  vd = dc{(double)v1.x, (double)v1.y};
  a2 = dsub(a2, dmul(vd, d_of(G[3][s])));
  a3 = dsub(a3, dmul(vd, d_of(G[4][s])));
  d = fmax((double)D[2][s], (double)EPSF);
  v2 = make_float2((float)(a2.x/d), (float)(a2.y/d));
  vd = dc{(double)v2.x, (double)v2.y};
  a3 = dsub(a3, dmul(vd, d_of(G[5][s])));
  d = fmax((double)D[3][s], (double)EPSF);
  v3 = make_float2((float)(a3.x/d), (float)(a3.y/d));
}

// T map: G[0..3]=(0,1..4)  G[4..6]=(1,2..4)  G[7..8]=(2,3..4)  G[9]=(3,4)
__device__ __forceinline__ void chainT(int s, const float2 (*A)[S_],
    const float (*D)[S_], const float2 (*G)[S_],
    float2& v0, float2& v1, float2& v2, float2& v3, float2& v4)
{
  dc a0 = d_of(A[0][s]), a1 = d_of(A[1][s]), a2 = d_of(A[2][s]);
  dc a3 = d_of(A[3][s]), a4 = d_of(A[4][s]);
  double d; dc vd;
  d = fmax((double)D[0][s], (double)EPSF);
  v0 = make_float2((float)(a0.x/d), (float)(a0.y/d));
  vd = dc{(double)v0.x, (double)v0.y};
  a1 = dsub(a1, dmul(vd, d_of(G[0][s])));
  a2 = dsub(a2, dmul(vd, d_of(G[1][s])));
  a3 = dsub(a3, dmul(vd, d_of(G[2][s])));
  a4 = dsub(a4, dmul(vd, d_of(G[3][s])));
  d = fmax((double)D[1][s], (double)EPSF);
  v1 = make_float2((float)(a1.x/d), (float)(a1.y/d));
  vd = dc{(double)v1.x, (double)v1.y};
  a2 = dsub(a2, dmul(vd, d_of(G[4][s])));
  a3 = dsub(a3, dmul(vd, d_of(G[5][s])));
  a4 = dsub(a4, dmul(vd, d_of(G[6][s])));
  d = fmax((double)D[2][s], (double)EPSF);
  v2 = make_float2((float)(a2.x/d), (float)(a2.y/d));
  vd = dc{(double)v2.x, (double)v2.y};
  a3 = dsub(a3, dmul(vd, d_of(G[7][s])));
  a4 = dsub(a4, dmul(vd, d_of(G[8][s])));
  d = fmax((double)D[3][s], (double)EPSF);
  v3 = make_float2((float)(a3.x/d), (float)(a3.y/d));
  vd = dc{(double)v3.x, (double)v3.y};
  a4 = dsub(a4, dmul(vd, d_of(G[9][s])));
  d = fmax((double)D[4][s], (double)EPSF);
  v4 = make_float2((float)(a4.x/d), (float)(a4.y/d));
}

// ---------------------------------------------------------------------------
// KM: one full _one_iter for one (b,f), blocked-ISS, merged wave-tasks, f32.
// ---------------------------------------------------------------------------
template<bool FIRST, bool FINAL>
__global__ __launch_bounds__(512, 2) void k_main(const float* __restrict__ Xre,
    const float* __restrict__ Xim, float2* __restrict__ Yg, float2* __restrict__ Wg,
    float2* __restrict__ Hg, float2* __restrict__ Cxxg,
    float2* __restrict__ Cbxg, const float* __restrict__ deng,
    const float* __restrict__ gsumg, float2* __restrict__ out2)
{
  __shared__ float2 Xl[C_*N_];
  __shared__ float2 Yl[S_*N_];
  __shared__ float  wl[S_*N_];
  __shared__ float2 Wl[S_*C_];
  __shared__ float2 Hl[S_*C_*T_];
  __shared__ float2 Jl[K_*S_];
  __shared__ float2 Al[S_*C_];
  __shared__ float  redl[2*64];
  __shared__ float2 AresF[T_][S_];
  __shared__ float  DresF[T_][S_];
  __shared__ float2 GresF[10][S_];
  __shared__ float2 Cxl[C_*C_];
  __shared__ float2 Cbl[C_*T_*C_];

  int p = blockIdx.x; int b = p / F_; int f = p - b*F_;
  int tid = threadIdx.x;
  int lane = tid & 63, wid = tid >> 6;
  const int nA = tid;
  const int nB = tid + NTHR;
  const bool hasB = (nB < N_);
  const int nBs = hasB ? nB : 0;

  for (int i = tid; i < C_*N_; i += NTHR){
    int c = i / N_, n = i - c*N_;
    size_t gi = ((size_t)(b*C_+c)*F_ + f)*N_ + n;
    Xl[i] = make_float2(Xre[gi], Xim[gi]);
  }
  if (tid < 128) redl[tid] = 0.f;

  float gv0 = fmaxf(gsumg[b*S_+0] * (1.f/((float)F_*(float)N_)), EPSF);
  float gv1 = fmaxf(gsumg[b*S_+1] * (1.f/((float)F_*(float)N_)), EPSF);
  float ig0 = 1.f / fmaxf(sqrtf(gv0), EPSF);
  float ig1 = 1.f / fmaxf(sqrtf(gv1), EPSF);

  float wA0 = gv0 / fmaxf(2.f*sqrtf(deng[(b*S_+0)*N_+nA]), MODEL_EPSF);
  float wA1 = gv1 / fmaxf(2.f*sqrtf(deng[(b*S_+1)*N_+nA]), MODEL_EPSF);
  float wB0 = 0.f, wB1 = 0.f;
  wl[nA] = wA0; wl[N_+nA] = wA1;
  if (hasB){
    wB0 = gv0 / fmaxf(2.f*sqrtf(deng[(b*S_+0)*N_+nB]), MODEL_EPSF);
    wB1 = gv1 / fmaxf(2.f*sqrtf(deng[(b*S_+1)*N_+nB]), MODEL_EPSF);
    wl[nB] = wB0; wl[N_+nB] = wB1;
  }

  if (FIRST){
    if (tid < S_*C_){
      int s = tid / C_, c = tid - s*C_;
      Wl[tid] = make_float2((s==c) ? (s ? ig1 : ig0) : 0.f, 0.f);
    }
    if (tid < S_*C_*T_) Hl[tid] = make_float2(0.f, 0.f);
  } else {
    if (tid < S_*C_){
      float ig = (tid / C_) ? ig1 : ig0;
      float2 w = Wg[(size_t)p*S_*C_ + tid];
      Wl[tid] = make_float2(w.x*ig, w.y*ig);
    }
    if (tid < S_*C_*T_){
      float ig = (tid / (C_*T_)) ? ig1 : ig0;
      float2 h = Hg[(size_t)p*S_*C_*T_ + tid];
      Hl[tid] = make_float2(h.x*ig, h.y*ig);
    }
  }
  __syncthreads();

  // Y init/load (LDS), scaled
  if (FIRST){
    float2 x0 = Xl[nA], x1 = Xl[N_+nA];
    Yl[nA]    = make_float2(x0.x*ig0, x0.y*ig0);
    Yl[N_+nA] = make_float2(x1.x*ig1, x1.y*ig1);
    if (hasB){
      float2 u0 = Xl[nB], u1 = Xl[N_+nB];
      Yl[nB]    = make_float2(u0.x*ig0, u0.y*ig0);
      Yl[N_+nB] = make_float2(u1.x*ig1, u1.y*ig1);
    }
  } else {
    float2 t0 = Yg[((size_t)p*S_+0)*N_+nA];
    float2 t1 = Yg[((size_t)p*S_+1)*N_+nA];
    Yl[nA]    = make_float2(t0.x*ig0, t0.y*ig0);
    Yl[N_+nA] = make_float2(t1.x*ig1, t1.y*ig1);
    if (hasB){
      float2 u0 = Yg[((size_t)p*S_+0)*N_+nB];
      float2 u1 = Yg[((size_t)p*S_+1)*N_+nB];
      Yl[nB]    = make_float2(u0.x*ig0, u0.y*ig0);
      Yl[N_+nB] = make_float2(u1.x*ig1, u1.y*ig1);
    }
  }

  if (FIRST){
    // merged covariances: task (d,c) computes Cxx(d,c) + Cbx(d,0..4,c)
    const float inv_n = 1.0f / (float)N_;
    for (int e = wid; e < 36; e += 8){
      int d = e / C_, c2 = e - d*C_;
      const float2* Xd = Xl + d*N_;
      const float2* Xc2 = Xl + c2*N_;
      float rr[6], ri[6];
      #pragma unroll
      for (int q = 0; q < 6; ++q){ rr[q]=0.f; ri[q]=0.f; }
      for (int n = lane; n < N_; n += 64){
        float2 xb = Xc2[n];
        float2 x5 = Xd[n];
        rr[5] += x5.x*xb.x + x5.y*xb.y;
        ri[5] += x5.y*xb.x - x5.x*xb.y;
        #pragma unroll
        for (int t = 0; t < T_; ++t){
          const int lag = DLY - t;
          float2 xa = (n >= lag) ? Xd[n-lag] : make_float2(0.f,0.f);
          rr[t] += xa.x*xb.x + xa.y*xb.y;
          ri[t] += xa.y*xb.x - xa.x*xb.y;
        }
      }
      #pragma unroll
      for (int q = 0; q < 6; ++q){
        float a = wred(rr[q]), bb = wred(ri[q]);
        if (lane == 0){
          float2 r = make_float2(a*inv_n, bb*inv_n);
          if (q == 5){ Cxl[d*C_+c2] = r; Cxxg[(size_t)p*(C_*C_) + d*C_+c2] = r; }
          else {
            int idx = (d*T_+q)*C_+c2;
            Cbl[idx] = r; Cbxg[(size_t)p*(C_*T_*C_) + idx] = r;
          }
        }
      }
    }
  }
  __syncthreads();

  const float2* cx = FIRST ? (const float2*)Cxl : (const float2*)(Cxxg + (size_t)p*C_*C_);
  const float2* cb = FIRST ? (const float2*)Cbl : (const float2*)(Cbxg + (size_t)p*C_*T_*C_);

  bg_update(tid, Wl, Hl, Al, Jl, cx, cb);

  // ---- source rounds ----
  src_round<0>(tid, lane, wid, hasB, nA, nBs, redl, Yl, Wl, Hl, wA0, wA1, wB0, wB1);
  src_round<1>(tid, lane, wid, hasB, nA, nBs, redl, Yl, Wl, Hl, wA0, wA1, wB0, wB1);
  __syncthreads();   // Y visible to all waves

  // ---- Z group: 3 merged wave-tasks ----
  {
    if (wid == 0){
      // A + D for k=0..3
      float arr[4][2], ari[4][2], dd[4][2];
      #pragma unroll
      for (int k = 0; k < 4; ++k){
        arr[k][0]=arr[k][1]=0.f; ari[k][0]=ari[k][1]=0.f; dd[k][0]=dd[k][1]=0.f;
      }
      float2 J0a=Jl[0],J0b=Jl[1],J1a=Jl[2],J1b=Jl[3],J2a=Jl[4],J2b=Jl[5],J3a=Jl[6],J3b=Jl[7];
      for (int n = lane; n < N_; n += 64){
        float2 x0 = Xl[n], x1 = Xl[N_+n];
        float w0 = wl[n], w1 = wl[N_+n];
        float2 y0 = Yl[n], y1 = Yl[N_+n];
        float2 zz[4];
        zz[0] = csub(cadd(cmul(J0a,x0), cmul(J0b,x1)), Xl[(S_+0)*N_+n]);
        zz[1] = csub(cadd(cmul(J1a,x0), cmul(J1b,x1)), Xl[(S_+1)*N_+n]);
        zz[2] = csub(cadd(cmul(J2a,x0), cmul(J2b,x1)), Xl[(S_+2)*N_+n]);
        zz[3] = csub(cadd(cmul(J3a,x0), cmul(J3b,x1)), Xl[(S_+3)*N_+n]);
        #pragma unroll
        for (int k = 0; k < 4; ++k){
          float2 z = zz[k];
          float m = z.x*z.x + z.y*z.y;
          arr[k][0] += w0*(y0.x*z.x + y0.y*z.y);
          ari[k][0] += w0*(y0.y*z.x - y0.x*z.y);
          arr[k][1] += w1*(y1.x*z.x + y1.y*z.y);
          ari[k][1] += w1*(y1.y*z.x - y1.x*z.y);
          dd[k][0] += w0*m; dd[k][1] += w1*m;
        }
      }
      #pragma unroll
      for (int k = 0; k < 4; ++k)
        #pragma unroll
        for (int s = 0; s < 2; ++s){
          float a = wred(arr[k][s]), bb = wred(ari[k][s]), d2 = wred(dd[k][s]);
          if (lane == 0){ AresF[k][s] = make_float2(a, bb); DresF[k][s] = d2; }
        }
    } else if (wid == 1){
      // G pairs (0,1),(0,2),(0,3) -> q=0,1,2
      float grr[3][2], gri[3][2];
      #pragma unroll
      for (int q = 0; q < 3; ++q){ grr[q][0]=grr[q][1]=0.f; gri[q][0]=gri[q][1]=0.f; }
      float2 J0a=Jl[0],J0b=Jl[1],J1a=Jl[2],J1b=Jl[3],J2a=Jl[4],J2b=Jl[5],J3a=Jl[6],J3b=Jl[7];
      for (int n = lane; n < N_; n += 64){
        float2 x0 = Xl[n], x1 = Xl[N_+n];
        float w0 = wl[n], w1 = wl[N_+n];
        float2 za = csub(cadd(cmul(J0a,x0), cmul(J0b,x1)), Xl[(S_+0)*N_+n]);
        float2 zz[3];
        zz[0] = csub(cadd(cmul(J1a,x0), cmul(J1b,x1)), Xl[(S_+1)*N_+n]);
        zz[1] = csub(cadd(cmul(J2a,x0), cmul(J2b,x1)), Xl[(S_+2)*N_+n]);
        zz[2] = csub(cadd(cmul(J3a,x0), cmul(J3b,x1)), Xl[(S_+3)*N_+n]);
        #pragma unroll
        for (int q = 0; q < 3; ++q){
          float2 zb = zz[q];
          float pr = za.x*zb.x + za.y*zb.y;
          float pi = za.y*zb.x - za.x*zb.y;
          grr[q][0] += w0*pr; gri[q][0] += w0*pi;
          grr[q][1] += w1*pr; gri[q][1] += w1*pi;
        }
      }
      #pragma unroll
      for (int q = 0; q < 3; ++q)
        #pragma unroll
        for (int s = 0; s < 2; ++s){
          float a = wred(grr[q][s]), bb = wred(gri[q][s]);
          if (lane == 0) GresF[q][s] = make_float2(a, bb);
        }
    } else if (wid == 2){
      // G pairs (1,2),(1,3),(2,3) -> q=3,4,5
      float grr[3][2], gri[3][2];
      #pragma unroll
      for (int q = 0; q < 3; ++q){ grr[q][0]=grr[q][1]=0.f; gri[q][0]=gri[q][1]=0.f; }
      float2 J1a=Jl[2],J1b=Jl[3],J2a=Jl[4],J2b=Jl[5],J3a=Jl[6],J3b=Jl[7];
      for (int n = lane; n < N_; n += 64){
        float2 x0 = Xl[n], x1 = Xl[N_+n];
        float w0 = wl[n], w1 = wl[N_+n];
        float2 z1 = csub(cadd(cmul(J1a,x0), cmul(J1b,x1)), Xl[(S_+1)*N_+n]);
        float2 z2 = csub(cadd(cmul(J2a,x0), cmul(J2b,x1)), Xl[(S_+2)*N_+n]);
        float2 z3 = csub(cadd(cmul(J3a,x0), cmul(J3b,x1)), Xl[(S_+3)*N_+n]);
        float pr, pi;
        pr = z1.x*z2.x + z1.y*z2.y; pi = z1.y*z2.x - z1.x*z2.y;
        grr[0][0] += wl[n]*pr; gri[0][0] += wl[n]*pi;
        grr[0][1] += w1*pr;    gri[0][1] += w1*pi;
        pr = z1.x*z3.x + z1.y*z3.y; pi = z1.y*z3.x - z1.x*z3.y;
        grr[1][0] += w0*pr; gri[1][0] += w0*pi;
        grr[1][1] += w1*pr; gri[1][1] += w1*pi;
        pr = z2.x*z3.x + z2.y*z3.y; pi = z2.y*z3.x - z2.x*z3.y;
        grr[2][0] += w0*pr; gri[2][0] += w0*pi;
        grr[2][1] += w1*pr; gri[2][1] += w1*pi;
      }
      #pragma unroll
      for (int q = 0; q < 3; ++q)
        #pragma unroll
        for (int s = 0; s < 2; ++s){
          float a = wred(grr[q][s]), bb = wred(gri[q][s]);
          if (lane == 0) GresF[3+q][s] = make_float2(a, bb);
        }
    }
    __syncthreads();

    // chain (redundant, named scalars)
    float2 vz0s0, vz1s0, vz2s0, vz3s0;
    float2 vz0s1, vz1s1, vz2s1, vz3s1;
    chainZ(0, AresF, DresF, GresF, vz0s0, vz1s0, vz2s0, vz3s0);
    chainZ(1, AresF, DresF, GresF, vz0s1, vz1s1, vz2s1, vz3s1);

    // deferred Y update (own frames)
    {
      float2 x0 = Xl[nA], x1 = Xl[N_+nA];
      float2 y0 = Yl[nA], y1 = Yl[N_+nA];
      float2 z;
      z = csub(cadd(cmul(Jl[0], x0), cmul(Jl[1], x1)), Xl[(S_+0)*N_+nA]);
      y0 = csub(y0, cmul(vz0s0, z)); y1 = csub(y1, cmul(vz0s1, z));
      z = csub(cadd(cmul(Jl[2], x0), cmul(Jl[3], x1)), Xl[(S_+1)*N_+nA]);
      y0 = csub(y0, cmul(vz1s0, z)); y1 = csub(y1, cmul(vz1s1, z));
      z = csub(cadd(cmul(Jl[4], x0), cmul(Jl[5], x1)), Xl[(S_+2)*N_+nA]);
      y0 = csub(y0, cmul(vz2s0, z)); y1 = csub(y1, cmul(vz2s1, z));
      z = csub(cadd(cmul(Jl[6], x0), cmul(Jl[7], x1)), Xl[(S_+3)*N_+nA]);
      y0 = csub(y0, cmul(vz3s0, z)); y1 = csub(y1, cmul(vz3s1, z));
      Yl[nA] = y0; Yl[N_+nA] = y1;
      if (hasB){
        float2 u0 = Xl[nB], u1 = Xl[N_+nB];
        float2 p0 = Yl[nB], p1 = Yl[N_+nB];
        z = csub(cadd(cmul(Jl[0], u0), cmul(Jl[1], u1)), Xl[(S_+0)*N_+nB]);
        p0 = csub(p0, cmul(vz0s0, z)); p1 = csub(p1, cmul(vz0s1, z));
        z = csub(cadd(cmul(Jl[2], u0), cmul(Jl[3], u1)), Xl[(S_+1)*N_+nB]);
        p0 = csub(p0, cmul(vz1s0, z)); p1 = csub(p1, cmul(vz1s1, z));
        z = csub(cadd(cmul(Jl[4], u0), cmul(Jl[5], u1)), Xl[(S_+2)*N_+nB]);
        p0 = csub(p0, cmul(vz2s0, z)); p1 = csub(p1, cmul(vz2s1, z));
        z = csub(cadd(cmul(Jl[6], u0), cmul(Jl[7], u1)), Xl[(S_+3)*N_+nB]);
        p0 = csub(p0, cmul(vz3s0, z)); p1 = csub(p1, cmul(vz3s1, z));
        Yl[nB] = p0; Yl[N_+nB] = p1;
      }
    }
    // W updates
    if (tid == 0){
      Wl[0] = csub(Wl[0], cadd(cadd(cmul(vz0s0,Jl[0]), cmul(vz1s0,Jl[2])),
                               cadd(cmul(vz2s0,Jl[4]), cmul(vz3s0,Jl[6]))));
      Wl[1] = csub(Wl[1], cadd(cadd(cmul(vz0s0,Jl[1]), cmul(vz1s0,Jl[3])),
                               cadd(cmul(vz2s0,Jl[5]), cmul(vz3s0,Jl[7]))));
      Wl[S_+0] = cadd(Wl[S_+0], vz0s0);
      Wl[S_+1] = cadd(Wl[S_+1], vz1s0);
      Wl[S_+2] = cadd(Wl[S_+2], vz2s0);
      Wl[S_+3] = cadd(Wl[S_+3], vz3s0);
      Wl[C_+0] = csub(Wl[C_+0], cadd(cadd(cmul(vz0s1,Jl[0]), cmul(vz1s1,Jl[2])),
                                     cadd(cmul(vz2s1,Jl[4]), cmul(vz3s1,Jl[6]))));
      Wl[C_+1] = csub(Wl[C_+1], cadd(cadd(cmul(vz0s1,Jl[1]), cmul(vz1s1,Jl[3])),
                                     cadd(cmul(vz2s1,Jl[5]), cmul(vz3s1,Jl[7]))));
      Wl[C_+S_+0] = cadd(Wl[C_+S_+0], vz0s1);
      Wl[C_+S_+1] = cadd(Wl[C_+S_+1], vz1s1);
      Wl[C_+S_+2] = cadd(Wl[C_+S_+2], vz2s1);
      Wl[C_+S_+3] = cadd(Wl[C_+S_+3], vz3s1);
    }
    __syncthreads();
  }

  // ---- tap groups: channel c; 5 merged wave-tasks (1 A+D, 4 G-anchors) ----
  for (int c = 0; c < C_; ++c){
    const float2* Xc = Xl + c*N_;
    if (wid == 0){
      float arr[5][2], ari[5][2], dd[5][2];
      #pragma unroll
      for (int t = 0; t < 5; ++t){
        arr[t][0]=arr[t][1]=0.f; ari[t][0]=ari[t][1]=0.f; dd[t][0]=dd[t][1]=0.f;
      }
      for (int n = lane; n < N_; n += 64){
        float w0 = wl[n], w1 = wl[N_+n];
        float2 y0 = Yl[n], y1 = Yl[N_+n];
        #pragma unroll
        for (int t = 0; t < 5; ++t){
          const int lag = DLY - t;
          float2 x = (n >= lag) ? Xc[n-lag] : make_float2(0.f,0.f);
          float m = x.x*x.x + x.y*x.y;
          arr[t][0] += w0*(y0.x*x.x + y0.y*x.y);
          ari[t][0] += w0*(y0.y*x.x - y0.x*x.y);
          arr[t][1] += w1*(y1.x*x.x + y1.y*x.y);
          ari[t][1] += w1*(y1.y*x.x - y1.x*x.y);
          dd[t][0] += w0*m; dd[t][1] += w1*m;
        }
      }
      #pragma unroll
      for (int t = 0; t < 5; ++t)
        #pragma unroll
        for (int s = 0; s < 2; ++s){
          float a = wred(arr[t][s]), bb = wred(ari[t][s]), d2 = wred(dd[t][s]);
          if (lane == 0){ AresF[t][s] = make_float2(a, bb); DresF[t][s] = d2; }
        }
    }
    else if (wid == 1) tapG<0>(lane, Xc, wl, GresF);
    else if (wid == 2) tapG<1>(lane, Xc, wl, GresF);
    else if (wid == 3) tapG<2>(lane, Xc, wl, GresF);
    else if (wid == 4) tapG<3>(lane, Xc, wl, GresF);
    __syncthreads();

    // chain (redundant, named scalars)
    float2 vt0s0, vt1s0, vt2s0, vt3s0, vt4s0;
    float2 vt0s1, vt1s1, vt2s1, vt3s1, vt4s1;
    chainT(0, AresF, DresF, GresF, vt0s0, vt1s0, vt2s0, vt3s0, vt4s0);
    chainT(1, AresF, DresF, GresF, vt0s1, vt1s1, vt2s1, vt3s1, vt4s1);

    // deferred Y update
    {
      float2 y0 = Yl[nA], y1 = Yl[N_+nA];
      float2 x;
      x = (nA >= 6) ? Xc[nA-6] : make_float2(0.f,0.f);
      y0 = csub(y0, cmul(vt0s0, x)); y1 = csub(y1, cmul(vt0s1, x));
      x = (nA >= 5) ? Xc[nA-5] : make_float2(0.f,0.f);
      y0 = csub(y0, cmul(vt1s0, x)); y1 = csub(y1, cmul(vt1s1, x));
      x = (nA >= 4) ? Xc[nA-4] : make_float2(0.f,0.f);
      y0 = csub(y0, cmul(vt2s0, x)); y1 = csub(y1, cmul(vt2s1, x));
      x = (nA >= 3) ? Xc[nA-3] : make_float2(0.f,0.f);
      y0 = csub(y0, cmul(vt3s0, x)); y1 = csub(y1, cmul(vt3s1, x));
      x = (nA >= 2) ? Xc[nA-2] : make_float2(0.f,0.f);
      y0 = csub(y0, cmul(vt4s0, x)); y1 = csub(y1, cmul(vt4s1, x));
      Yl[nA] = y0; Yl[N_+nA] = y1;
      if (hasB){
        float2 p0 = Yl[nB], p1 = Yl[N_+nB];
        x = Xc[nB-6]; p0 = csub(p0, cmul(vt0s0, x)); p1 = csub(p1, cmul(vt0s1, x));
        x = Xc[nB-5]; p0 = csub(p0, cmul(vt1s0, x)); p1 = csub(p1, cmul(vt1s1, x));
        x = Xc[nB-4]; p0 = csub(p0, cmul(vt2s0, x)); p1 = csub(p1, cmul(vt2s1, x));
        x = Xc[nB-3]; p0 = csub(p0, cmul(vt3s0, x)); p1 = csub(p1, cmul(vt3s1, x));
        x = Xc[nB-2]; p0 = csub(p0, cmul(vt4s0, x)); p1 = csub(p1, cmul(vt4s1, x));
        Yl[nB] = p0; Yl[N_+nB] = p1;
      }
    }
    // H updates
    if (tid == 0){
      Hl[(0*C_+c)*T_+0] = cadd(Hl[(0*C_+c)*T_+0], vt0s0);
      Hl[(0*C_+c)*T_+1] = cadd(Hl[(0*C_+c)*T_+1], vt1s0);
      Hl[(0*C_+c)*T_+2] = cadd(Hl[(0*C_+c)*T_+2], vt2s0);
      Hl[(0*C_+c)*T_+3] = cadd(Hl[(0*C_+c)*T_+3], vt3s0);
      Hl[(0*C_+c)*T_+4] = cadd(Hl[(0*C_+c)*T_+4], vt4s0);
      Hl[(1*C_+c)*T_+0] = cadd(Hl[(1*C_+c)*T_+0], vt0s1);
      Hl[(1*C_+c)*T_+1] = cadd(Hl[(1*C_+c)*T_+1], vt1s1);
      Hl[(1*C_+c)*T_+2] = cadd(Hl[(1*C_+c)*T_+2], vt2s1);
      Hl[(1*C_+c)*T_+3] = cadd(Hl[(1*C_+c)*T_+3], vt3s1);
      Hl[(1*C_+c)*T_+4] = cadd(Hl[(1*C_+c)*T_+4], vt4s1);
    }
    __syncthreads();
  }

  if (!FINAL){
    Yg[((size_t)p*S_+0)*N_+nA] = Yl[nA];
    Yg[((size_t)p*S_+1)*N_+nA] = Yl[N_+nA];
    if (hasB){
      Yg[((size_t)p*S_+0)*N_+nB] = Yl[nB];
      Yg[((size_t)p*S_+1)*N_+nB] = Yl[N_+nB];
    }
    if (tid < S_*C_)    Wg[(size_t)p*S_*C_ + tid]    = Wl[tid];
    if (tid < S_*C_*T_) Hg[(size_t)p*S_*C_*T_ + tid] = Hl[tid];
  } else {
    bg_update(tid, Wl, Hl, Al, Jl, cx, cb);   // final J

    float2 oA0 = make_float2(0.f,0.f), oA1 = oA0, oB0 = oA0, oB1 = oA0;
    #pragma unroll
    for (int d = 0; d < C_; ++d){
      float2 x = Xl[d*N_+nA];
      oA0 = cadd(oA0, cmul(Wl[d],    x));
      oA1 = cadd(oA1, cmul(Wl[C_+d], x));
    }
    #pragma unroll
    for (int t = 0; t < T_; ++t){
      int m = nA - (DLY - t);
      if (m >= 0){
        #pragma unroll
        for (int d = 0; d < C_; ++d){
          float2 x = Xl[d*N_+m];
          oA0 = csub(oA0, cmul(Hl[d*T_+t],      x));
          oA1 = csub(oA1, cmul(Hl[(C_+d)*T_+t], x));
        }
      }
    }
    if (hasB){
      #pragma unroll
      for (int d = 0; d < C_; ++d){
        float2 x = Xl[d*N_+nB];
        oB0 = cadd(oB0, cmul(Wl[d],    x));
        oB1 = cadd(oB1, cmul(Wl[C_+d], x));
      }
      #pragma unroll
      for (int t = 0; t < T_; ++t){
        int m = nB - (DLY - t);
        #pragma unroll
        for (int d = 0; d < C_; ++d){
          float2 x = Xl[d*N_+m];
          oB0 = csub(oB0, cmul(Hl[d*T_+t],      x));
          oB1 = csub(oB1, cmul(Hl[(C_+d)*T_+t], x));
        }
      }
    }

    if (tid == 0){
      dc Bm[2][2];
      #pragma unroll
      for (int s2 = 0; s2 < S_; ++s2)
        #pragma unroll
        for (int k = 0; k < S_; ++k){
          dc acc = d_of(Wl[s2*C_+k]);
          #pragma unroll
          for (int cc = 0; cc < K_; ++cc)
            acc = dadd(acc, dmul(d_of(Wl[s2*C_+S_+cc]), d_of(Jl[cc*S_+k])));
          Bm[s2][k] = acc;
        }
      dc G00 = dc{Bm[0][0].x + PB_EPSD, Bm[0][0].y};
      dc G01 = Bm[1][0];
      dc G10 = Bm[0][1];
      dc G11 = dc{Bm[1][1].x + PB_EPSD, Bm[1][1].y};
      dc det = dsub(dmul(G00, G11), dmul(G01, G10));
      dc a0 = ddiv(G11, det);
      dc a1 = ddiv(dc{-G10.x, -G10.y}, det);
      Al[0] = make_float2((float)a0.x, (float)a0.y);
      Al[1] = make_float2((float)a1.x, (float)a1.y);
    }
    __syncthreads();
    float2 s0 = Al[0], s1 = Al[1];
    out2[((size_t)(b*S_+0)*F_ + f)*N_ + nA] = cmul(oA0, s0);
    out2[((size_t)(b*S_+1)*F_ + f)*N_ + nA] = cmul(oA1, s1);
    if (hasB){
      out2[((size_t)(b*S_+0)*F_ + f)*N_ + nB] = cmul(oB0, s0);
      out2[((size_t)(b*S_+1)*F_ + f)*N_ + nB] = cmul(oB1, s1);
    }
  }
}

// ---------------------------------------------------------------------------
extern "C" void kernel_launch(void* const* d_in, const int* in_sizes, int n_in,
                              void* d_out, int out_size, void* d_ws, size_t ws_size,
                              hipStream_t stream)
{
  const float* Xre = (const float*)d_in[0];
  const float* Xim = (const float*)d_in[1];
  int B = in_sizes[0] / (C_*F_*N_);
  int P = B*F_;

  float2* Yg    = (float2*)d_ws;
  float2* Wg    = Yg    + (size_t)P*S_*N_;
  float2* Hg    = Wg    + (size_t)P*S_*C_;
  float2* Cxxg  = Hg    + (size_t)P*S_*C_*T_;
  float2* Cbxg  = Cxxg  + (size_t)P*C_*C_;
  float*  deng0 = (float*)(Cbxg + (size_t)P*C_*T_*C_);
  float*  deng1 = deng0 + (size_t)B*S_*N_;
  float*  gsum0 = deng1 + (size_t)B*S_*N_;
  float*  gsum1 = gsum0 + (size_t)B*S_;
  float2* out2  = (float2*)d_out;

  size_t zeroBytes = (2*(size_t)B*S_*N_ + 2*(size_t)B*S_) * sizeof(float);
  int WG = B*S_*8*16;

  hipMemsetAsync(deng0, 0, zeroBytes, stream);
  // iteration 0 (covariances computed inside k_main<FIRST>)
  k_weights_x<<<WG, 128, 0, stream>>>(Xre, Xim, deng0, gsum0);
  k_main<true,false><<<P, 512, 0, stream>>>(Xre, Xim, Yg, Wg, Hg, Cxxg, Cbxg,
                                            deng0, gsum0, nullptr);
  // iteration 1 + finalization
  k_weights_y<<<WG, 128, 0, stream>>>(Yg, deng1, gsum1);
  k_main<false,true><<<P, 512, 0, stream>>>(Xre, Xim, Yg, Wg, Hg, Cxxg, Cbxg,
                                            deng1, gsum1, out2);
}